// Round 15
// baseline (221.614 us; speedup 1.0000x reference)
//
#include <hip/hip_runtime.h>
#include <hip/hip_cooperative_groups.h>

namespace cg = cooperative_groups;

#define DEV __device__ __forceinline__

typedef __attribute__((ext_vector_type(4))) float f32x4;
typedef __bf16 bf16_t;
typedef __attribute__((ext_vector_type(4))) bf16_t bf16x4;
typedef __attribute__((ext_vector_type(8))) bf16_t bf16x8;
typedef __attribute__((ext_vector_type(8))) unsigned short us8;
typedef __attribute__((ext_vector_type(4))) unsigned short us4;

// B=8, S=2048, D_MODEL=256, H=4, DEPTH=64, BH=32, M=B*S=16384

DEV unsigned short f2bf(float f) {
  bf16_t h = (bf16_t)f;
  return __builtin_bit_cast(unsigned short, h);
}

DEV void gl2lds16(const void* g, void* l) {
  __builtin_amdgcn_global_load_lds(
      (const __attribute__((address_space(1))) unsigned int*)g,
      (__attribute__((address_space(3))) unsigned int*)l, 16, 0, 0);
}

DEV f32x4 mfma16(bf16x8 a, bf16x8 b, f32x4 c) {
  return __builtin_amdgcn_mfma_f32_16x16x32_bf16(a, b, c, 0, 0, 0);
}

// ---- ONE cooperative megakernel: prep -> qkv -> attn+out, 2 grid syncs. ----
// 256 blocks x 512 threads, 160 KB LDS, exactly 1 block/CU (co-resident).
__global__ __launch_bounds__(512, 1) void mega(
    const float* __restrict__ v, const float* __restrict__ kk,
    const float* __restrict__ q, const float* __restrict__ mask,
    const float* __restrict__ wq, const float* __restrict__ bq,
    const float* __restrict__ wk, const float* __restrict__ bk,
    const float* __restrict__ wv, const float* __restrict__ bv,
    const float* __restrict__ wo, const float* __restrict__ bo,
    unsigned short* __restrict__ wt, float* __restrict__ mprep,
    int* __restrict__ proc,
    unsigned short* __restrict__ Qh, unsigned short* __restrict__ Kh,
    unsigned short* __restrict__ VhT, float* __restrict__ out) {
  __shared__ __align__(16) unsigned short L[81920];   // 160 KB
  cg::grid_group grid = cg::this_grid();
  const int bid = blockIdx.x;
  const int t = threadIdx.x, lane = t & 63, w = t >> 6;   // 8 waves
  const int lr = lane & 15, lg = lane >> 4;
  const int lx = lr & 7;

  // ================= PHASE 0: prep (W transpose + mask prescale/prune) ======
  if (bid < 64) {
    float* T = (float*)L;                       // 64*65 f32 = 16.6 KB
    const int mat = bid >> 4, tn = (bid >> 2) & 3, tk = bid & 3;
    const int n0 = tn * 64, k0 = tk * 64;
    const float* W = (mat == 0) ? wq : (mat == 1) ? wk : (mat == 2) ? wv : wo;
    if (t < 256) {
      const int r0 = t >> 4, c = (t & 15) * 4;
#pragma unroll
      for (int i = 0; i < 4; ++i) {
        int rr = r0 + i * 16;
        f32x4 x = *(const f32x4*)(W + (k0 + rr) * 256 + n0 + c);
#pragma unroll
        for (int j = 0; j < 4; ++j) T[(c + j) * 65 + rr] = x[j];
      }
    }
    __syncthreads();
    if (t < 256) {
#pragma unroll
      for (int i = 0; i < 2; ++i) {
        int u = t + i * 256;
        int n = u >> 3, seg = u & 7;
        us8 pk;
#pragma unroll
        for (int j = 0; j < 8; ++j) pk[j] = f2bf(T[n * 65 + seg * 8 + j]);
        *(us8*)(&wt[mat * 65536 + (n0 + n) * 256 + k0 + seg * 8]) = pk;
      }
    }
  } else if (bid < 72) {
    float* tm = (float*)&L[65536];
    const int b = bid - 64;
    const float* mr = mask + b * 2048;
    if (t < 256) {
      f32x4 x0 = *(const f32x4*)(mr + t * 8);
      f32x4 x1 = *(const f32x4*)(mr + t * 8 + 4);
      *(f32x4*)(mprep + b * 2048 + t * 8)     = x0 * -1.442695041e9f;
      *(f32x4*)(mprep + b * 2048 + t * 8 + 4) = x1 * -1.442695041e9f;
      float mn = fminf(fminf(fminf(x0[0], x0[1]), fminf(x0[2], x0[3])),
                       fminf(fminf(x1[0], x1[1]), fminf(x1[2], x1[3])));
      mn = fminf(mn, __shfl_xor(mn, 1));
      mn = fminf(mn, __shfl_xor(mn, 2));
      mn = fminf(mn, __shfl_xor(mn, 4));
      if ((t & 7) == 0) tm[t >> 3] = mn;
    }
    __syncthreads();
    if (t == 0) {
      int base = b * 33, cnt = 0;
      float minm = 1e30f;
      for (int tl = 0; tl < 32; ++tl) {
        float vv = tm[tl];
        int need = (vv < minm + 1.45e-6f) ? 1 : 0;
        proc[512 + b * 32 + tl] = need;
        if (need) { proc[base + 1 + cnt] = tl; ++cnt; }
        minm = fminf(minm, vv);
      }
      proc[base] = cnt;
    }
  }
  __threadfence();
  grid.sync();

  // ================= PHASE 1: QKV projection (job loop) =====================
  // jobs: p = jb>>9 (0..2), strip = jb&511 (M32 row-strips). 6 jobs/block max.
  {
    unsigned short* At = &L[0];          // 32 x 64  (4 KB)
    unsigned short* Bt = &L[2048];       // 256 x 64 (32 KB)
    const int w2 = w >> 1, e = w & 1;    // head, col-half
    for (int jb = bid; jb < 1536; jb += 256) {
      const int p = jb >> 9, strip = jb & 511;
      if (p != 0 && proc[512 + ((strip >> 6) << 5) + ((strip >> 1) & 31)] == 0)
        continue;
      const float* A    = (p == 0) ? q : (p == 1) ? kk : v;
      const float* bias = (p == 0) ? bq : (p == 1) ? bk : bv;
      const unsigned short* WT = wt + p * 65536;
      const int m0 = strip * 32;

      f32x4 acc[2][2] = {};   // [m][cg]
      for (int j = 0; j < 4; ++j) {
        const int k0 = j * 64;
#pragma unroll
        for (int i = 0; i < 4; ++i) {          // B: 2048 units / 512 thr
          int u = t + i * 512;
          int row = u >> 3, g = (u & 7) ^ (row & 7);
          gl2lds16(WT + row * 256 + k0 + g * 8, &Bt[u * 8]);
        }
        if (t < 256) {                          // A: 256 units
          const int as_row = t >> 3, as_seg = t & 7;
          f32x4 x0 = *(const f32x4*)(A + (m0 + as_row) * 256 + k0 + as_seg * 8);
          f32x4 x1 = *(const f32x4*)(A + (m0 + as_row) * 256 + k0 + as_seg * 8 + 4);
          us8 pk;
#pragma unroll
          for (int jj = 0; jj < 4; ++jj) { pk[jj] = f2bf(x0[jj]); pk[jj + 4] = f2bf(x1[jj]); }
          *(us8*)(&At[(as_row << 6) + ((as_seg ^ (as_row & 7)) << 3)]) = pk;
        }
        __syncthreads();
#pragma unroll
        for (int ds = 0; ds < 2; ++ds) {
          const int ku = (ds << 2) | lg;
          const int phys = (ku ^ lx) << 3;
          bf16x8 af[2], bfr[2];
#pragma unroll
          for (int m = 0; m < 2; ++m)
            af[m] = *(const bf16x8*)(&At[((m * 16 + lr) << 6) + phys]);
#pragma unroll
          for (int cgi = 0; cgi < 2; ++cgi)
            bfr[cgi] = *(const bf16x8*)(&Bt[((w2 * 64 + e * 32 + cgi * 16 + lr) << 6) + phys]);
#pragma unroll
          for (int m = 0; m < 2; ++m)
#pragma unroll
            for (int cgi = 0; cgi < 2; ++cgi)
              acc[m][cgi] = mfma16(af[m], bfr[cgi], acc[m][cgi]);
        }
        __syncthreads();
      }

      const int b = m0 >> 11, s0 = m0 & 2047;
      const int bh = b * 4 + w2;
#pragma unroll
      for (int cgi = 0; cgi < 2; ++cgi) {
        int d = e * 32 + cgi * 16 + lr;
        float bb = bias[w2 * 64 + d];
#pragma unroll
        for (int m = 0; m < 2; ++m) {
          int sb = s0 + m * 16 + lg * 4;
          if (p == 2) {
            us4 o;
#pragma unroll
            for (int r = 0; r < 4; ++r) o[r] = f2bf(acc[m][cgi][r] + bb);
            *(us4*)(&VhT[(bh * 64 + d) * 2048 + sb]) = o;
          } else {
            unsigned short* Cp = (p == 0) ? Qh : Kh;
#pragma unroll
            for (int r = 0; r < 4; ++r)
              Cp[(bh * 2048 + sb + r) * 64 + d] = f2bf(acc[m][cgi][r] + bb);
          }
        }
      }
    }
  }
  __threadfence();
  grid.sync();

  // ================= PHASE 2: fused attention + output projection ==========
  {
    const int b = bid >> 5;
    const int q0 = (bid & 31) * 64;
    const int h = w >> 1, ch = w & 1;
    const int bh = b * 4 + h;
    const float* mrow = mprep + b * 2048;
    const int* plist = proc + b * 33;
    const int lgh = lg >> 1, lgo = (lg & 1) * 4;

    bf16x8 qf[2][2];
#pragma unroll
    for (int cc = 0; cc < 2; ++cc)
#pragma unroll
      for (int ds = 0; ds < 2; ++ds)
        qf[cc][ds] = *(const bf16x8*)(Qh + (bh * 2048 + q0 + ch * 32 + cc * 16 + lr) * 64 + ds * 32 + lg * 8);

    f32x4 accO[2][4] = {};
    float mrun[2] = {-3.0e38f, -3.0e38f}, lrun[2] = {0.f, 0.f};

#define STAGE(buf, kv)                                                        \
    {                                                                         \
      _Pragma("unroll")                                                       \
      for (int i = 0; i < 4; ++i) {                                           \
        int u = t + i * 512;                                                  \
        int hh = u >> 9, vv = u & 511;                                        \
        int row = vv >> 3, g = (vv & 7) ^ (row & 7);                          \
        gl2lds16(Kh + ((b * 4 + hh) * 2048 + (kv) + row) * 64 + g * 8,        \
                 &L[((buf) * 16384 + hh * 4096 + vv * 8)]);                   \
        gl2lds16(VhT + ((b * 4 + hh) * 64 + row) * 2048 + (kv) + g * 8,       \
                 &L[(32768 + (buf) * 16384 + hh * 4096 + vv * 8)]);           \
      }                                                                       \
    }

    const int cnt = plist[0];
    STAGE(0, plist[1] * 64)
    __syncthreads();
    int cur = 0;

    for (int j = 0; j < cnt; ++j) {
      const int kv0 = plist[1 + j] * 64;
      if (j + 1 < cnt) STAGE(cur ^ 1, plist[2 + j] * 64)

      const int kb_base = cur * 16384 + h * 4096;
      const int vb_base = 32768 + kb_base;

#pragma unroll
      for (int cc = 0; cc < 2; ++cc) {
        f32x4 accS[4] = {};
        __builtin_amdgcn_s_setprio(1);
#pragma unroll
        for (int kb = 0; kb < 4; ++kb)
#pragma unroll
          for (int ds = 0; ds < 2; ++ds) {
            bf16x8 kf = *(const bf16x8*)(&L[kb_base + (((kb * 16 + lr) << 3) | (((ds << 2) | lg) ^ lx)) * 8]);
            accS[kb] = mfma16(kf, qf[cc][ds], accS[kb]);
          }
        __builtin_amdgcn_s_setprio(0);

        f32x4 sv[4];
#pragma unroll
        for (int kb = 0; kb < 4; ++kb) {
          f32x4 mk = *(const f32x4*)(mrow + kv0 + kb * 16 + lg * 4);
          sv[kb] = accS[kb] * 0.1803368801f + mk;
        }
        float mx0 = fmaxf(fmaxf(sv[0][0], sv[0][1]), fmaxf(sv[0][2], sv[0][3]));
        float mx1 = fmaxf(fmaxf(sv[1][0], sv[1][1]), fmaxf(sv[1][2], sv[1][3]));
        float mx2 = fmaxf(fmaxf(sv[2][0], sv[2][1]), fmaxf(sv[2][2], sv[2][3]));
        float mx3 = fmaxf(fmaxf(sv[3][0], sv[3][1]), fmaxf(sv[3][2], sv[3][3]));
        float mx = fmaxf(fmaxf(mx0, mx1), fmaxf(mx2, mx3));
        mx = fmaxf(mx, __shfl_xor(mx, 16));
        mx = fmaxf(mx, __shfl_xor(mx, 32));
        float mnew = fmaxf(mrun[cc], mx);
        float al = __builtin_amdgcn_exp2f(mrun[cc] - mnew);
        mrun[cc] = mnew;

        float px[4][4];
        float lsum = 0.f;
#pragma unroll
        for (int kb = 0; kb < 4; ++kb) {
          float s = 0.f;
#pragma unroll
          for (int r = 0; r < 4; ++r) {
            px[kb][r] = __builtin_amdgcn_exp2f(sv[kb][r] - mnew);
            s += px[kb][r];
          }
          lsum += s;
        }
        lsum += __shfl_xor(lsum, 16);
        lsum += __shfl_xor(lsum, 32);
        lrun[cc] = lrun[cc] * al + lsum;
#pragma unroll
        for (int db = 0; db < 4; ++db) accO[cc][db] *= al;

        bf16x8 pf[2];
#pragma unroll
        for (int ks = 0; ks < 2; ++ks) {
          bf16x8 p;
#pragma unroll
          for (int r = 0; r < 4; ++r) {
            p[r]     = (bf16_t)px[2 * ks][r];
            p[r + 4] = (bf16_t)px[2 * ks + 1][r];
          }
          pf[ks] = p;
        }

        __builtin_amdgcn_s_setprio(1);
#pragma unroll
        for (int ks = 0; ks < 2; ++ks)
#pragma unroll
          for (int db = 0; db < 4; ++db) {
            int row = db * 16 + lr;
            int u0 = (row << 3) | (((ks << 2) | lgh) ^ lx);
            int u1 = (row << 3) | (((ks << 2) | 2 | lgh) ^ lx);
            bf16x4 v0 = *(const bf16x4*)(&L[vb_base + u0 * 8 + lgo]);
            bf16x4 v1 = *(const bf16x4*)(&L[vb_base + u1 * 8 + lgo]);
            bf16x8 vf = __builtin_shufflevector(v0, v1, 0, 1, 2, 3, 4, 5, 6, 7);
            accO[cc][db] = mfma16(vf, pf[ks], accO[cc][db]);
          }
        __builtin_amdgcn_s_setprio(0);
      }

      __syncthreads();
      cur ^= 1;
    }
#undef STAGE

    // epilogue: O -> LDS bf16 (swizzled), stage WoT, out = O @ Wo + bo
#pragma unroll
    for (int cc = 0; cc < 2; ++cc) {
      const float inv = __builtin_amdgcn_rcpf(lrun[cc]);
      const int row = ch * 32 + cc * 16 + lr;
#pragma unroll
      for (int db = 0; db < 4; ++db) {
        us4 o;
#pragma unroll
        for (int r = 0; r < 4; ++r) o[r] = f2bf(accO[cc][db][r] * inv);
        int un = h * 8 + db * 2 + (lg >> 1);
        int phys = (un & 24) | ((un & 7) ^ (row & 7));
        *(us4*)(&L[65536 + row * 256 + phys * 8 + (lg & 1) * 4]) = o;
      }
    }
    __syncthreads();

    const unsigned short* WT = wt + 3 * 65536;
#pragma unroll
    for (int i = 0; i < 16; ++i) {
      int u = t + i * 512;
      int row = u >> 5, un = u & 31;
      int g = (un & 24) | ((un & 7) ^ (row & 7));
      gl2lds16(WT + row * 256 + g * 8, &L[u * 8]);
    }
    __syncthreads();

    f32x4 acc[4][2] = {};
#pragma unroll
    for (int ds = 0; ds < 8; ++ds) {
      const int ku = ds * 4 + lg;
      const int phys = ((ku & 24) | ((ku & 7) ^ lx)) << 3;
      bf16x8 af[4], bfr[2];
#pragma unroll
      for (int m = 0; m < 4; ++m)
        af[m] = *(const bf16x8*)(&L[65536 + (m * 16 + lr) * 256 + phys]);
#pragma unroll
      for (int n = 0; n < 2; ++n)
        bfr[n] = *(const bf16x8*)(&L[(w * 32 + n * 16 + lr) * 256 + phys]);
#pragma unroll
      for (int m = 0; m < 4; ++m)
#pragma unroll
        for (int n = 0; n < 2; ++n)
          acc[m][n] = mfma16(af[m], bfr[n], acc[m][n]);
    }

#pragma unroll
    for (int cgi = 0; cgi < 2; ++cgi) {
      int col = w * 32 + cgi * 16 + lr;
      float bb = bo[col];
#pragma unroll
      for (int m = 0; m < 4; ++m) {
        int rowg = b * 2048 + q0 + m * 16 + lg * 4;
#pragma unroll
        for (int r = 0; r < 4; ++r)
          out[(rowg + r) * 256 + col] = acc[m][cgi][r] + bb;
      }
    }
  }
}

extern "C" void kernel_launch(void* const* d_in, const int* in_sizes, int n_in,
                              void* d_out, int out_size, void* d_ws, size_t ws_size,
                              hipStream_t stream) {
  const float* v    = (const float*)d_in[0];
  const float* k    = (const float*)d_in[1];
  const float* q    = (const float*)d_in[2];
  const float* mask = (const float*)d_in[3];
  const float* wq   = (const float*)d_in[4];
  const float* bq   = (const float*)d_in[5];
  const float* wk   = (const float*)d_in[6];
  const float* bk   = (const float*)d_in[7];
  const float* wv   = (const float*)d_in[8];
  const float* bv   = (const float*)d_in[9];
  const float* wo   = (const float*)d_in[10];
  const float* bo   = (const float*)d_in[11];
  float* out = (float*)d_out;
  char* ws = (char*)d_ws;

  // ws: wt 524288 | mprep 65536 | proc 4096 | Qh | Kh | VhT (8 MB each)
  unsigned short* wt  = (unsigned short*)(ws);
  float*          mp  = (float*)(ws + 524288);
  int*            pr  = (int*)(ws + 589824);
  unsigned short* Qh  = (unsigned short*)(ws + 593920);
  unsigned short* Kh  = (unsigned short*)(ws + 593920 + 8388608);
  unsigned short* VhT = (unsigned short*)(ws + 593920 + 2 * 8388608);

  void* kargs[] = {
    (void*)&v, (void*)&k, (void*)&q, (void*)&mask,
    (void*)&wq, (void*)&bq, (void*)&wk, (void*)&bk,
    (void*)&wv, (void*)&bv, (void*)&wo, (void*)&bo,
    (void*)&wt, (void*)&mp, (void*)&pr,
    (void*)&Qh, (void*)&Kh, (void*)&VhT, (void*)&out
  };
  hipLaunchCooperativeKernel((void*)mega, dim3(256), dim3(512), kargs, 0, stream);
}

// Round 16
// 65.337 us; speedup vs baseline: 3.3919x; 3.3919x over previous
//
#include <hip/hip_runtime.h>

#define DEV __device__ __forceinline__

typedef __attribute__((ext_vector_type(4))) float f32x4;
typedef __bf16 bf16_t;
typedef __attribute__((ext_vector_type(4))) bf16_t bf16x4;
typedef __attribute__((ext_vector_type(8))) bf16_t bf16x8;
typedef __attribute__((ext_vector_type(8))) unsigned short us8;
typedef __attribute__((ext_vector_type(4))) unsigned short us4;

// B=8, S=2048, D_MODEL=256, H=4, DEPTH=64, BH=32, M=B*S=16384

DEV unsigned short f2bf(float f) {
  bf16_t h = (bf16_t)f;
  return __builtin_bit_cast(unsigned short, h);
}

DEV void gl2lds16(const void* g, void* l) {
  __builtin_amdgcn_global_load_lds(
      (const __attribute__((address_space(1))) unsigned int*)g,
      (__attribute__((address_space(3))) unsigned int*)l, 16, 0, 0);
}

DEV f32x4 mfma16(bf16x8 a, bf16x8 b, f32x4 c) {
  return __builtin_amdgcn_mfma_f32_16x16x32_bf16(a, b, c, 0, 0, 0);
}

// ---- prep: W transpose (blocks 0..63); per-batch mask prescale+prune (64..71) ----
__global__ __launch_bounds__(256) void prep_w(
    const float* __restrict__ wq, const float* __restrict__ wk,
    const float* __restrict__ wv, const float* __restrict__ wo,
    const float* __restrict__ mask,
    unsigned short* __restrict__ wt, float* __restrict__ mprep,
    int* __restrict__ proc) {
  const int t = threadIdx.x;
  if (blockIdx.x < 64) {
    __shared__ float T[64 * 65];
    const int mat = blockIdx.x >> 4, tn = (blockIdx.x >> 2) & 3, tk = blockIdx.x & 3;
    const int n0 = tn * 64, k0 = tk * 64;
    const float* W = (mat == 0) ? wq : (mat == 1) ? wk : (mat == 2) ? wv : wo;
    const int r0 = t >> 4, c = (t & 15) * 4;
#pragma unroll
    for (int i = 0; i < 4; ++i) {
      int rr = r0 + i * 16;
      f32x4 x = *(const f32x4*)(W + (k0 + rr) * 256 + n0 + c);
#pragma unroll
      for (int j = 0; j < 4; ++j) T[(c + j) * 65 + rr] = x[j];
    }
    __syncthreads();
#pragma unroll
    for (int i = 0; i < 2; ++i) {
      int u = t + i * 256;
      int n = u >> 3, seg = u & 7;
      us8 pk;
#pragma unroll
      for (int j = 0; j < 8; ++j) pk[j] = f2bf(T[n * 65 + seg * 8 + j]);
      *(us8*)(&wt[mat * 65536 + (n0 + n) * 256 + k0 + seg * 8]) = pk;
    }
  } else {
    __shared__ float tm[32];
    const int b = blockIdx.x - 64;
    const float* mr = mask + b * 2048;
    f32x4 x0 = *(const f32x4*)(mr + t * 8);
    f32x4 x1 = *(const f32x4*)(mr + t * 8 + 4);
    *(f32x4*)(mprep + b * 2048 + t * 8)     = x0 * -1.442695041e9f;
    *(f32x4*)(mprep + b * 2048 + t * 8 + 4) = x1 * -1.442695041e9f;
    float mn = fminf(fminf(fminf(x0[0], x0[1]), fminf(x0[2], x0[3])),
                     fminf(fminf(x1[0], x1[1]), fminf(x1[2], x1[3])));
    mn = fminf(mn, __shfl_xor(mn, 1));
    mn = fminf(mn, __shfl_xor(mn, 2));
    mn = fminf(mn, __shfl_xor(mn, 4));
    if ((t & 7) == 0) tm[t >> 3] = mn;
    __syncthreads();
    if (t == 0) {
      int base = b * 33, cnt = 0;
      float minm = 1e30f;
      for (int tl = 0; tl < 32; ++tl) {
        float v = tm[tl];
        int need = (v < minm + 1.45e-6f) ? 1 : 0;
        proc[512 + b * 32 + tl] = need;
        if (need) { proc[base + 1 + cnt] = tl; ++cnt; }
        minm = fminf(minm, v);
      }
      proc[base] = cnt;
    }
  }
}

// ---- QKV projection: SINGLE-BARRIER FULL-K. Tile M32 x N64 x K256(all).
// Stage A(16KB, reg) + B(32KB, gl2lds) = 48KB -> 3 blocks/CU; ONE barrier;
// 16 MFMA/wave; epilogue. All staging in flight at once (maximal async depth).
__global__ __launch_bounds__(256, 3) void gemm_qkv(
    const float* __restrict__ Aq, const float* __restrict__ Ak, const float* __restrict__ Av,
    const float* __restrict__ bq, const float* __restrict__ bk, const float* __restrict__ bv,
    const unsigned short* __restrict__ wt, const int* __restrict__ proc,
    unsigned short* __restrict__ Qh, unsigned short* __restrict__ Kh,
    unsigned short* __restrict__ VhT) {
  const int p = blockIdx.z;
  const int strip = blockIdx.x;              // 0..511, 32-row strips
  if (p != 0 && proc[512 + ((strip >> 6) << 5) + ((strip >> 1) & 31)] == 0) return;

  __shared__ __align__(16) unsigned short At[32 * 256];   // 16 KB
  __shared__ __align__(16) unsigned short Bt[64 * 256];   // 32 KB
  const float* A    = (p == 0) ? Aq : (p == 1) ? Ak : Av;
  const float* bias = (p == 0) ? bq : (p == 1) ? bk : bv;
  const unsigned short* WT = wt + p * 65536;
  const int nq = blockIdx.y;                 // head / 64-col group
  const int t = threadIdx.x, lane = t & 63, w = t >> 6;
  const int lr = lane & 15, lg = lane >> 4;
  const int lx = lr & 7;
  const int m0 = strip * 32;

  // stage B: 64 rows x 32 us8-units, pre-swizzled global source
#pragma unroll
  for (int i = 0; i < 8; ++i) {
    int u = t + i * 256;
    int row = u >> 5, un = u & 31;
    int g = (un & 24) | ((un & 7) ^ (row & 7));
    gl2lds16(WT + (nq * 64 + row) * 256 + g * 8, &Bt[u * 8]);
  }
  // stage A: 32 rows x 256 k, f32 -> bf16 via regs (8 threads/row, 32 f32 each)
  {
    const int row = t >> 3, seg = (t & 7) * 4;   // un = seg..seg+3
    const float* src = A + (m0 + row) * 256 + seg * 8;
#pragma unroll
    for (int j = 0; j < 4; ++j) {
      f32x4 x0 = *(const f32x4*)(src + j * 8);
      f32x4 x1 = *(const f32x4*)(src + j * 8 + 4);
      us8 pk;
#pragma unroll
      for (int jj = 0; jj < 4; ++jj) { pk[jj] = f2bf(x0[jj]); pk[jj + 4] = f2bf(x1[jj]); }
      int un = seg + j;
      *(us8*)(&At[row * 256 + (((un & 24) | ((un & 7) ^ (row & 7))) << 3)]) = pk;
    }
  }
  __syncthreads();   // the ONLY barrier

  f32x4 acc[2] = {};
#pragma unroll
  for (int ds = 0; ds < 8; ++ds) {
    const int ku = ds * 4 + lg;
    const int phys = ((ku & 24) | ((ku & 7) ^ lx)) << 3;
    bf16x8 bfr = *(const bf16x8*)(&Bt[(w * 16 + lr) * 256 + phys]);
#pragma unroll
    for (int m = 0; m < 2; ++m) {
      bf16x8 af = *(const bf16x8*)(&At[(m * 16 + lr) * 256 + phys]);
      acc[m] = mfma16(af, bfr, acc[m]);
    }
  }

  const int b = m0 >> 11, s0 = m0 & 2047;
  const int d = w * 16 + lr;                 // 0..63, head = nq
  const int bh = b * 4 + nq;
  const float bb = bias[nq * 64 + d];
#pragma unroll
  for (int m = 0; m < 2; ++m) {
    int sb = s0 + m * 16 + lg * 4;
    if (p == 2) {
      us4 o;
#pragma unroll
      for (int r = 0; r < 4; ++r) o[r] = f2bf(acc[m][r] + bb);
      *(us4*)(&VhT[(bh * 64 + d) * 2048 + sb]) = o;
    } else {
      unsigned short* Cp = (p == 0) ? Qh : Kh;
#pragma unroll
      for (int r = 0; r < 4; ++r)
        Cp[(bh * 2048 + sb + r) * 64 + d] = f2bf(acc[m][r] + bb);
    }
  }
}

// ---- standalone flash attention (R10-proven: 32KB LDS, 4 blocks/CU) ----
__global__ __launch_bounds__(256) void attn(
    const unsigned short* __restrict__ Qh, const unsigned short* __restrict__ Kh,
    const unsigned short* __restrict__ VhT, const float* __restrict__ mprep,
    const int* __restrict__ proc,
    unsigned short* __restrict__ Aout) {
  __shared__ __align__(16) unsigned short Kt[2][4096];
  __shared__ __align__(16) unsigned short Vt[2][4096];
  const int bh = blockIdx.y;
  const int q0 = blockIdx.x * 64;
  const int t = threadIdx.x, lane = t & 63, wid = t >> 6;
  const int lr = lane & 15, lg = lane >> 4;
  const int qrow = q0 + wid * 16;
  const unsigned short* Kbase = Kh + bh * 131072;
  const unsigned short* Vbase = VhT + bh * 131072;
  const float* mrow = mprep + (bh >> 2) * 2048;
  const int* plist = proc + (bh >> 2) * 33;
  const int lx = lr & 7;
  const int lgh = lg >> 1, lgo = (lg & 1) * 4;

  bf16x8 qf[2];
#pragma unroll
  for (int ds = 0; ds < 2; ++ds)
    qf[ds] = *(const bf16x8*)(Qh + (bh * 2048 + qrow + lr) * 64 + ds * 32 + lg * 8);

  f32x4 accO[4] = {};
  float mrun = -3.0e38f, lrun = 0.f;

#define STAGE(buf, kv)                                                        \
  {                                                                           \
    _Pragma("unroll")                                                         \
    for (int i = 0; i < 2; ++i) {                                             \
      int u = t + i * 256;                                                    \
      int row = u >> 3, g = (u & 7) ^ (row & 7);                              \
      gl2lds16(Kbase + ((kv) + row) * 64 + g * 8, &Kt[buf][u * 8]);           \
      gl2lds16(Vbase + row * 2048 + (kv) + g * 8, &Vt[buf][u * 8]);           \
    }                                                                         \
  }

  const int cnt = plist[0];
  STAGE(0, plist[1] * 64)
  __syncthreads();
  int cur = 0;

  for (int j = 0; j < cnt; ++j) {
    const int kv0 = plist[1 + j] * 64;
    if (j + 1 < cnt) STAGE(cur ^ 1, plist[2 + j] * 64)

    f32x4 accS[4] = {};
    __builtin_amdgcn_s_setprio(1);
#pragma unroll
    for (int kb = 0; kb < 4; ++kb)
#pragma unroll
      for (int ds = 0; ds < 2; ++ds) {
        bf16x8 kf = *(const bf16x8*)(&Kt[cur][((kb * 16 + lr) << 3 | (((ds << 2) | lg) ^ lx)) * 8]);
        accS[kb] = mfma16(kf, qf[ds], accS[kb]);
      }
    __builtin_amdgcn_s_setprio(0);

    f32x4 sv[4];
#pragma unroll
    for (int kb = 0; kb < 4; ++kb) {
      f32x4 mk = *(const f32x4*)(mrow + kv0 + kb * 16 + lg * 4);
      sv[kb] = accS[kb] * 0.1803368801f + mk;
    }
    float mx0 = fmaxf(fmaxf(sv[0][0], sv[0][1]), fmaxf(sv[0][2], sv[0][3]));
    float mx1 = fmaxf(fmaxf(sv[1][0], sv[1][1]), fmaxf(sv[1][2], sv[1][3]));
    float mx2 = fmaxf(fmaxf(sv[2][0], sv[2][1]), fmaxf(sv[2][2], sv[2][3]));
    float mx3 = fmaxf(fmaxf(sv[3][0], sv[3][1]), fmaxf(sv[3][2], sv[3][3]));
    float mx = fmaxf(fmaxf(mx0, mx1), fmaxf(mx2, mx3));
    mx = fmaxf(mx, __shfl_xor(mx, 16));
    mx = fmaxf(mx, __shfl_xor(mx, 32));
    float mnew = fmaxf(mrun, mx);
    float al = __builtin_amdgcn_exp2f(mrun - mnew);
    mrun = mnew;

    float px[4][4];
    float lsum = 0.f;
#pragma unroll
    for (int kb = 0; kb < 4; ++kb) {
      float s = 0.f;
#pragma unroll
      for (int r = 0; r < 4; ++r) {
        px[kb][r] = __builtin_amdgcn_exp2f(sv[kb][r] - mnew);
        s += px[kb][r];
      }
      lsum += s;
    }
    lsum += __shfl_xor(lsum, 16);
    lsum += __shfl_xor(lsum, 32);
    lrun = lrun * al + lsum;
#pragma unroll
    for (int db = 0; db < 4; ++db) accO[db] *= al;

    bf16x8 pf[2];
#pragma unroll
    for (int ks = 0; ks < 2; ++ks) {
      bf16x8 p;
#pragma unroll
      for (int r = 0; r < 4; ++r) {
        p[r]     = (bf16_t)px[2 * ks][r];
        p[r + 4] = (bf16_t)px[2 * ks + 1][r];
      }
      pf[ks] = p;
    }

    __builtin_amdgcn_s_setprio(1);
#pragma unroll
    for (int ks = 0; ks < 2; ++ks)
#pragma unroll
      for (int db = 0; db < 4; ++db) {
        int row = db * 16 + lr;
        int u0 = (row << 3) | (((ks << 2) | lgh) ^ lx);
        int u1 = (row << 3) | (((ks << 2) | 2 | lgh) ^ lx);
        bf16x4 v0 = *(const bf16x4*)(&Vt[cur][u0 * 8 + lgo]);
        bf16x4 v1 = *(const bf16x4*)(&Vt[cur][u1 * 8 + lgo]);
        bf16x8 vf = __builtin_shufflevector(v0, v1, 0, 1, 2, 3, 4, 5, 6, 7);
        accO[db] = mfma16(vf, pf[ks], accO[db]);
      }
    __builtin_amdgcn_s_setprio(0);

    __syncthreads();
    cur ^= 1;
  }
#undef STAGE

  const int b = bh >> 2, h = bh & 3;
  const float inv = __builtin_amdgcn_rcpf(lrun);
  const int q = qrow + lr;
#pragma unroll
  for (int db = 0; db < 4; ++db) {
    us4 o;
#pragma unroll
    for (int r = 0; r < 4; ++r) o[r] = f2bf(accO[db][r] * inv);
    *(us4*)(&Aout[(b * 2048 + q) * 256 + h * 64 + db * 16 + lg * 4]) = o;
  }
}

// ---- output projection: SINGLE-BARRIER FULL-K (A=Ao bf16 via gl2lds) ----
__global__ __launch_bounds__(256, 3) void gemm_out(
    const unsigned short* __restrict__ Aout, const unsigned short* __restrict__ wt,
    const float* __restrict__ bo, float* __restrict__ out) {
  __shared__ __align__(16) unsigned short At[32 * 256];   // 16 KB
  __shared__ __align__(16) unsigned short Bt[64 * 256];   // 32 KB
  const unsigned short* WT = wt + 3 * 65536;
  const int nq = blockIdx.y;
  const int t = threadIdx.x, lane = t & 63, w = t >> 6;
  const int lr = lane & 15, lg = lane >> 4;
  const int lx = lr & 7;
  const int m0 = blockIdx.x * 32;

#pragma unroll
  for (int i = 0; i < 8; ++i) {
    int u = t + i * 256;
    int row = u >> 5, un = u & 31;
    int g = (un & 24) | ((un & 7) ^ (row & 7));
    gl2lds16(WT + (nq * 64 + row) * 256 + g * 8, &Bt[u * 8]);
  }
#pragma unroll
  for (int i = 0; i < 4; ++i) {
    int u = t + i * 256;
    int row = u >> 5, un = u & 31;
    int g = (un & 24) | ((un & 7) ^ (row & 7));
    gl2lds16(Aout + (m0 + row) * 256 + g * 8, &At[u * 8]);
  }
  __syncthreads();   // the ONLY barrier

  f32x4 acc[2] = {};
#pragma unroll
  for (int ds = 0; ds < 8; ++ds) {
    const int ku = ds * 4 + lg;
    const int phys = ((ku & 24) | ((ku & 7) ^ lx)) << 3;
    bf16x8 bfr = *(const bf16x8*)(&Bt[(w * 16 + lr) * 256 + phys]);
#pragma unroll
    for (int m = 0; m < 2; ++m) {
      bf16x8 af = *(const bf16x8*)(&At[(m * 16 + lr) * 256 + phys]);
      acc[m] = mfma16(af, bfr, acc[m]);
    }
  }

  const int col = nq * 64 + w * 16 + lr;
  const float bb = bo[col];
#pragma unroll
  for (int m = 0; m < 2; ++m) {
    int rowb = m0 + m * 16 + lg * 4;
#pragma unroll
    for (int r = 0; r < 4; ++r)
      out[(rowb + r) * 256 + col] = acc[m][r] + bb;
  }
}

extern "C" void kernel_launch(void* const* d_in, const int* in_sizes, int n_in,
                              void* d_out, int out_size, void* d_ws, size_t ws_size,
                              hipStream_t stream) {
  const float* v    = (const float*)d_in[0];
  const float* k    = (const float*)d_in[1];
  const float* q    = (const float*)d_in[2];
  const float* mask = (const float*)d_in[3];
  const float* wq   = (const float*)d_in[4];
  const float* bq   = (const float*)d_in[5];
  const float* wk   = (const float*)d_in[6];
  const float* bk   = (const float*)d_in[7];
  const float* wv   = (const float*)d_in[8];
  const float* bv   = (const float*)d_in[9];
  const float* wo   = (const float*)d_in[10];
  const float* bo   = (const float*)d_in[11];
  float* out = (float*)d_out;
  char* ws = (char*)d_ws;

  // ws: wt 524288 | mprep 65536 | proc 4096 | Qh | Kh | VhT | Ao (8 MB each)
  unsigned short* wt  = (unsigned short*)(ws);
  float*          mp  = (float*)(ws + 524288);
  int*            pr  = (int*)(ws + 589824);
  unsigned short* Qh  = (unsigned short*)(ws + 593920);
  unsigned short* Kh  = (unsigned short*)(ws + 593920 + 8388608);
  unsigned short* VhT = (unsigned short*)(ws + 593920 + 2 * 8388608);
  unsigned short* Ao  = (unsigned short*)(ws + 593920 + 3 * 8388608);

  prep_w<<<dim3(72), dim3(256), 0, stream>>>(wq, wk, wv, wo, mask, wt, mp, pr);
  gemm_qkv<<<dim3(512, 4, 3), dim3(256), 0, stream>>>(q, k, v, bq, bk, bv, wt, pr, Qh, Kh, VhT);
  attn<<<dim3(32, 32), dim3(256), 0, stream>>>(Qh, Kh, VhT, mp, pr, Ao);
  gemm_out<<<dim3(512, 4), dim3(256), 0, stream>>>(Ao, wt, bo, out);
}

// Round 17
// 48.263 us; speedup vs baseline: 4.5918x; 1.3538x over previous
//
#include <hip/hip_runtime.h>

#define DEV __device__ __forceinline__

typedef __attribute__((ext_vector_type(4))) float f32x4;
typedef __bf16 bf16_t;
typedef __attribute__((ext_vector_type(4))) bf16_t bf16x4;
typedef __attribute__((ext_vector_type(8))) bf16_t bf16x8;
typedef __attribute__((ext_vector_type(8))) unsigned short us8;
typedef __attribute__((ext_vector_type(4))) unsigned short us4;

// B=8, S=2048, D_MODEL=256, H=4, DEPTH=64, BH=32, M=B*S=16384

DEV unsigned short f2bf(float f) {
  bf16_t h = (bf16_t)f;
  return __builtin_bit_cast(unsigned short, h);
}

DEV void gl2lds16(const void* g, void* l) {
  __builtin_amdgcn_global_load_lds(
      (const __attribute__((address_space(1))) unsigned int*)g,
      (__attribute__((address_space(3))) unsigned int*)l, 16, 0, 0);
}

DEV f32x4 mfma16(bf16x8 a, bf16x8 b, f32x4 c) {
  return __builtin_amdgcn_mfma_f32_16x16x32_bf16(a, b, c, 0, 0, 0);
}

// ---- prep: W transpose (blocks 0..63); per-batch COLUMN gather (64..71) ----
// Column s of batch b is invisible unless mask[s] < min_b + 1.45e-6 (sound:
// |0.18*qk| <= 180 and the dropped-logit gap is >= 1731 bits in log2 domain).
// Deterministic prefix-sum compaction into gidx/mc; padded to 64 with mc=-1e30.
__global__ __launch_bounds__(256) void prep_w(
    const float* __restrict__ wq, const float* __restrict__ wk,
    const float* __restrict__ wv, const float* __restrict__ wo,
    const float* __restrict__ mask,
    unsigned short* __restrict__ wt, float* __restrict__ mc,
    int* __restrict__ gidx, int* __restrict__ nct) {
  const int t = threadIdx.x;
  if (blockIdx.x < 64) {
    __shared__ float T[64 * 65];
    const int mat = blockIdx.x >> 4, tn = (blockIdx.x >> 2) & 3, tk = blockIdx.x & 3;
    const int n0 = tn * 64, k0 = tk * 64;
    const float* W = (mat == 0) ? wq : (mat == 1) ? wk : (mat == 2) ? wv : wo;
    const int r0 = t >> 4, c = (t & 15) * 4;
#pragma unroll
    for (int i = 0; i < 4; ++i) {
      int rr = r0 + i * 16;
      f32x4 x = *(const f32x4*)(W + (k0 + rr) * 256 + n0 + c);
#pragma unroll
      for (int j = 0; j < 4; ++j) T[(c + j) * 65 + rr] = x[j];
    }
    __syncthreads();
#pragma unroll
    for (int i = 0; i < 2; ++i) {
      int u = t + i * 256;
      int n = u >> 3, seg = u & 7;
      us8 pk;
#pragma unroll
      for (int j = 0; j < 8; ++j) pk[j] = f2bf(T[n * 65 + seg * 8 + j]);
      *(us8*)(&wt[mat * 65536 + (n0 + n) * 256 + k0 + seg * 8]) = pk;
    }
  } else {
    __shared__ float redf[256];
    __shared__ int redi[256];
    const int b = blockIdx.x - 64;
    const float* mr = mask + b * 2048;
    f32x4 x0 = *(const f32x4*)(mr + t * 8);
    f32x4 x1 = *(const f32x4*)(mr + t * 8 + 4);
    float mv[8];
#pragma unroll
    for (int j = 0; j < 4; ++j) { mv[j] = x0[j]; mv[4 + j] = x1[j]; }
    float mn = mv[0];
#pragma unroll
    for (int j = 1; j < 8; ++j) mn = fminf(mn, mv[j]);
    redf[t] = mn;
    __syncthreads();
    for (int s = 128; s > 0; s >>= 1) {
      if (t < s) redf[t] = fminf(redf[t], redf[t + s]);
      __syncthreads();
    }
    const float minb = redf[0];
    const float thr = minb + 1.45e-6f;
    int myc = 0;
#pragma unroll
    for (int j = 0; j < 8; ++j) myc += (mv[j] < thr) ? 1 : 0;
    redi[t] = myc;
    __syncthreads();
    for (int s = 1; s < 256; s <<= 1) {
      int add = (t >= s) ? redi[t - s] : 0;
      __syncthreads();
      redi[t] += add;
      __syncthreads();
    }
    int pos = redi[t] - myc;             // exclusive prefix (deterministic order)
    const int cntb = redi[255];
#pragma unroll
    for (int j = 0; j < 8; ++j)
      if (mv[j] < thr) {
        gidx[b * 2048 + pos] = t * 8 + j;
        mc[b * 2048 + pos] = (mv[j] - minb) * -1.442695041e9f;
        ++pos;
      }
    if (t == 0) {
      int nt = (cntb + 63) >> 6;
      if (nt < 1) nt = 1;
      nct[b] = nt;
      for (int j = cntb; j < nt * 64; ++j) {
        gidx[b * 2048 + j] = 0;          // valid row; weight forced to 0
        mc[b * 2048 + j] = -1.0e30f;
      }
    }
  }
}

// ---- Q projection only (R14 small-block structure): M32 x N256 x BK64 ----
__global__ __launch_bounds__(256, 4) void gemm_q(
    const float* __restrict__ Aq, const float* __restrict__ bq,
    const unsigned short* __restrict__ wt,
    unsigned short* __restrict__ Qh) {
  __shared__ __align__(16) unsigned short At[32 * 64];      // 4 KB
  __shared__ __align__(16) unsigned short Bt[256 * 64];     // 32 KB
  const unsigned short* WT = wt;
  const int t = threadIdx.x, lane = t & 63, w = t >> 6;     // 4 waves
  const int lr = lane & 15, lg = lane >> 4;
  const int lx = lr & 7;
  const int m0 = blockIdx.x * 32;

  const int as_row = t >> 3, as_seg = t & 7;
  const float* agp = Aq + (m0 + as_row) * 256 + as_seg * 8;

  f32x4 acc[2][4] = {};   // [m][cg]

  for (int j = 0; j < 4; ++j) {
    const int k0 = j * 64;
#pragma unroll
    for (int i = 0; i < 8; ++i) {
      int u = t + i * 256;
      int row = u >> 3, g = (u & 7) ^ (row & 7);
      gl2lds16(WT + row * 256 + k0 + g * 8, &Bt[u * 8]);
    }
    {
      f32x4 x0 = *(const f32x4*)(agp + k0);
      f32x4 x1 = *(const f32x4*)(agp + k0 + 4);
      us8 pk;
#pragma unroll
      for (int jj = 0; jj < 4; ++jj) { pk[jj] = f2bf(x0[jj]); pk[jj + 4] = f2bf(x1[jj]); }
      *(us8*)(&At[(as_row << 6) + ((as_seg ^ (as_row & 7)) << 3)]) = pk;
    }
    __syncthreads();

#pragma unroll
    for (int ds = 0; ds < 2; ++ds) {
      const int ku = (ds << 2) | lg;
      const int phys = (ku ^ lx) << 3;
      bf16x8 af[2], bfr[4];
#pragma unroll
      for (int m = 0; m < 2; ++m)
        af[m] = *(const bf16x8*)(&At[((m * 16 + lr) << 6) + phys]);
#pragma unroll
      for (int cg = 0; cg < 4; ++cg)
        bfr[cg] = *(const bf16x8*)(&Bt[((w * 64 + cg * 16 + lr) << 6) + phys]);
#pragma unroll
      for (int m = 0; m < 2; ++m)
#pragma unroll
        for (int cg = 0; cg < 4; ++cg)
          acc[m][cg] = mfma16(af[m], bfr[cg], acc[m][cg]);
    }
    __syncthreads();
  }

  const int b = m0 >> 11, s0 = m0 & 2047;
  const int bh = b * 4 + w;            // wave w = head w
#pragma unroll
  for (int cg = 0; cg < 4; ++cg) {
    int d = cg * 16 + lr;
    float bb = bq[w * 64 + d];
#pragma unroll
    for (int m = 0; m < 2; ++m) {
      int sb = s0 + m * 16 + lg * 4;
#pragma unroll
      for (int r = 0; r < 4; ++r)
        Qh[(bh * 2048 + sb + r) * 64 + d] = f2bf(acc[m][cg][r] + bb);
    }
  }
}

// ---- K/V projection for GATHERED rows only: 64 rows x N256 x K256, 1 barrier ----
// grid (32, 8, 2): gt, batch, p(0=K,1=V); early-exit when gt >= nct[b].
__global__ __launch_bounds__(512) void gemm_kv(
    const float* __restrict__ kin, const float* __restrict__ vin,
    const float* __restrict__ bk, const float* __restrict__ bv,
    const unsigned short* __restrict__ wt, const int* __restrict__ gidx,
    const int* __restrict__ nct,
    unsigned short* __restrict__ Khc, unsigned short* __restrict__ VhcT) {
  const int gt = blockIdx.x, b = blockIdx.y, p = blockIdx.z;
  if (gt >= nct[b]) return;

  __shared__ __align__(16) unsigned short At[64 * 256];     // 32 KB
  __shared__ __align__(16) unsigned short Bt[256 * 256];    // 128 KB
  const float* A    = p ? vin : kin;
  const float* bias = p ? bv : bk;
  const unsigned short* WT = wt + (p ? 2 : 1) * 65536;
  const int t = threadIdx.x, lane = t & 63, w = t >> 6;     // 8 waves
  const int lr = lane & 15, lg = lane >> 4;
  const int lx = lr & 7;
  const int* gi = gidx + b * 2048 + gt * 64;

#pragma unroll
  for (int i = 0; i < 16; ++i) {
    int u = t + i * 512;
    int row = u >> 5, un = u & 31;
    int g = (un & 24) | ((un & 7) ^ (row & 7));
    gl2lds16(WT + row * 256 + g * 8, &Bt[u * 8]);
  }
  {
    const int row = t >> 3, seg = (t & 7) * 4;
    const int srow = gi[row];
    const float* src = A + (b * 2048 + srow) * 256 + seg * 8;
#pragma unroll
    for (int j = 0; j < 4; ++j) {
      f32x4 x0 = *(const f32x4*)(src + j * 8);
      f32x4 x1 = *(const f32x4*)(src + j * 8 + 4);
      us8 pk;
#pragma unroll
      for (int jj = 0; jj < 4; ++jj) { pk[jj] = f2bf(x0[jj]); pk[jj + 4] = f2bf(x1[jj]); }
      int un = seg + j;
      *(us8*)(&At[row * 256 + (((un & 24) | ((un & 7) ^ (row & 7))) << 3)]) = pk;
    }
  }
  __syncthreads();

  f32x4 acc[4][2] = {};
#pragma unroll
  for (int ds = 0; ds < 8; ++ds) {
    const int ku = ds * 4 + lg;
    const int phys = ((ku & 24) | ((ku & 7) ^ lx)) << 3;
    bf16x8 af[4], bfr[2];
#pragma unroll
    for (int m = 0; m < 4; ++m)
      af[m] = *(const bf16x8*)(&At[(m * 16 + lr) * 256 + phys]);
#pragma unroll
    for (int n = 0; n < 2; ++n)
      bfr[n] = *(const bf16x8*)(&Bt[(w * 32 + n * 16 + lr) * 256 + phys]);
#pragma unroll
    for (int m = 0; m < 4; ++m)
#pragma unroll
      for (int n = 0; n < 2; ++n)
        acc[m][n] = mfma16(af[m], bfr[n], acc[m][n]);
  }

#pragma unroll
  for (int n = 0; n < 2; ++n) {
    int col = w * 32 + n * 16 + lr;
    float bb = bias[col];
    int h = col >> 6, d = col & 63;
    int bh = b * 4 + h;
#pragma unroll
    for (int m = 0; m < 4; ++m) {
      int pos = gt * 64 + m * 16 + lg * 4;
      if (p) {
        us4 o;
#pragma unroll
        for (int r = 0; r < 4; ++r) o[r] = f2bf(acc[m][n][r] + bb);
        *(us4*)(&VhcT[(bh * 64 + d) * 2048 + pos]) = o;
      } else {
#pragma unroll
        for (int r = 0; r < 4; ++r)
          Khc[(bh * 2048 + pos + r) * 64 + d] = f2bf(acc[m][n][r] + bb);
      }
    }
  }
}

// ---- FUSED attention + output projection over COMPACTED tiles (R14 body) ----
__global__ __launch_bounds__(512) void attn_out(
    const unsigned short* __restrict__ Qh, const unsigned short* __restrict__ Kh,
    const unsigned short* __restrict__ VhT, const float* __restrict__ mc,
    const int* __restrict__ nct, const unsigned short* __restrict__ wt,
    const float* __restrict__ bo, float* __restrict__ out) {
  __shared__ __align__(16) unsigned short L[81920];   // 160 KB
  const int b = blockIdx.y;
  const int q0 = blockIdx.x * 64;
  const int t = threadIdx.x, lane = t & 63, w = t >> 6;
  const int lr = lane & 15, lg = lane >> 4;
  const int h = w >> 1, ch = w & 1;
  const int bh = b * 4 + h;
  const float* mrow = mc + b * 2048;
  const int lx = lr & 7;
  const int lgh = lg >> 1, lgo = (lg & 1) * 4;

  bf16x8 qf[2][2];
#pragma unroll
  for (int cc = 0; cc < 2; ++cc)
#pragma unroll
    for (int ds = 0; ds < 2; ++ds)
      qf[cc][ds] = *(const bf16x8*)(Qh + (bh * 2048 + q0 + ch * 32 + cc * 16 + lr) * 64 + ds * 32 + lg * 8);

  f32x4 accO[2][4] = {};
  float mrun[2] = {-3.0e38f, -3.0e38f}, lrun[2] = {0.f, 0.f};

#define STAGE(buf, kv)                                                        \
  {                                                                           \
    _Pragma("unroll")                                                         \
    for (int i = 0; i < 4; ++i) {                                             \
      int u = t + i * 512;                                                    \
      int hh = u >> 9, vv = u & 511;                                          \
      int row = vv >> 3, g = (vv & 7) ^ (row & 7);                            \
      gl2lds16(Kh + ((b * 4 + hh) * 2048 + (kv) + row) * 64 + g * 8,          \
               &L[((buf) * 16384 + hh * 4096 + vv * 8)]);                     \
      gl2lds16(VhT + ((b * 4 + hh) * 64 + row) * 2048 + (kv) + g * 8,         \
               &L[(32768 + (buf) * 16384 + hh * 4096 + vv * 8)]);             \
    }                                                                         \
  }

  const int cnt = nct[b];                   // block-uniform
  STAGE(0, 0)
  __syncthreads();
  int cur = 0;

  for (int j = 0; j < cnt; ++j) {
    const int kv0 = j * 64;
    if (j + 1 < cnt) STAGE(cur ^ 1, kv0 + 64)

    const int kb_base = cur * 16384 + h * 4096;
    const int vb_base = 32768 + kb_base;

#pragma unroll
    for (int cc = 0; cc < 2; ++cc) {
      f32x4 accS[4] = {};
      __builtin_amdgcn_s_setprio(1);
#pragma unroll
      for (int kb = 0; kb < 4; ++kb)
#pragma unroll
        for (int ds = 0; ds < 2; ++ds) {
          bf16x8 kf = *(const bf16x8*)(&L[kb_base + (((kb * 16 + lr) << 3) | (((ds << 2) | lg) ^ lx)) * 8]);
          accS[kb] = mfma16(kf, qf[cc][ds], accS[kb]);
        }
      __builtin_amdgcn_s_setprio(0);

      f32x4 sv[4];
#pragma unroll
      for (int kb = 0; kb < 4; ++kb) {
        f32x4 mk = *(const f32x4*)(mrow + kv0 + kb * 16 + lg * 4);
        sv[kb] = accS[kb] * 0.1803368801f + mk;
      }
      float mx0 = fmaxf(fmaxf(sv[0][0], sv[0][1]), fmaxf(sv[0][2], sv[0][3]));
      float mx1 = fmaxf(fmaxf(sv[1][0], sv[1][1]), fmaxf(sv[1][2], sv[1][3]));
      float mx2 = fmaxf(fmaxf(sv[2][0], sv[2][1]), fmaxf(sv[2][2], sv[2][3]));
      float mx3 = fmaxf(fmaxf(sv[3][0], sv[3][1]), fmaxf(sv[3][2], sv[3][3]));
      float mx = fmaxf(fmaxf(mx0, mx1), fmaxf(mx2, mx3));
      mx = fmaxf(mx, __shfl_xor(mx, 16));
      mx = fmaxf(mx, __shfl_xor(mx, 32));
      float mnew = fmaxf(mrun[cc], mx);
      float al = __builtin_amdgcn_exp2f(mrun[cc] - mnew);
      mrun[cc] = mnew;

      float px[4][4];
      float lsum = 0.f;
#pragma unroll
      for (int kb = 0; kb < 4; ++kb) {
        float s = 0.f;
#pragma unroll
        for (int r = 0; r < 4; ++r) {
          px[kb][r] = __builtin_amdgcn_exp2f(sv[kb][r] - mnew);
          s += px[kb][r];
        }
        lsum += s;
      }
      lsum += __shfl_xor(lsum, 16);
      lsum += __shfl_xor(lsum, 32);
      lrun[cc] = lrun[cc] * al + lsum;
#pragma unroll
      for (int db = 0; db < 4; ++db) accO[cc][db] *= al;

      bf16x8 pf[2];
#pragma unroll
      for (int ks = 0; ks < 2; ++ks) {
        bf16x8 p;
#pragma unroll
        for (int r = 0; r < 4; ++r) {
          p[r]     = (bf16_t)px[2 * ks][r];
          p[r + 4] = (bf16_t)px[2 * ks + 1][r];
        }
        pf[ks] = p;
      }

      __builtin_amdgcn_s_setprio(1);
#pragma unroll
      for (int ks = 0; ks < 2; ++ks)
#pragma unroll
        for (int db = 0; db < 4; ++db) {
          int row = db * 16 + lr;
          int u0 = (row << 3) | (((ks << 2) | lgh) ^ lx);
          int u1 = (row << 3) | (((ks << 2) | 2 | lgh) ^ lx);
          bf16x4 v0 = *(const bf16x4*)(&L[vb_base + u0 * 8 + lgo]);
          bf16x4 v1 = *(const bf16x4*)(&L[vb_base + u1 * 8 + lgo]);
          bf16x8 vf = __builtin_shufflevector(v0, v1, 0, 1, 2, 3, 4, 5, 6, 7);
          accO[cc][db] = mfma16(vf, pf[ks], accO[cc][db]);
        }
      __builtin_amdgcn_s_setprio(0);
    }

    __syncthreads();
    cur ^= 1;
  }
#undef STAGE

  // epilogue: O -> LDS bf16 (swizzled), stage WoT, out = O @ Wo + bo
#pragma unroll
  for (int cc = 0; cc < 2; ++cc) {
    const float inv = __builtin_amdgcn_rcpf(lrun[cc]);
    const int row = ch * 32 + cc * 16 + lr;
#pragma unroll
    for (int db = 0; db < 4; ++db) {
      us4 o;
#pragma unroll
      for (int r = 0; r < 4; ++r) o[r] = f2bf(accO[cc][db][r] * inv);
      int un = h * 8 + db * 2 + (lg >> 1);
      int phys = (un & 24) | ((un & 7) ^ (row & 7));
      *(us4*)(&L[65536 + row * 256 + phys * 8 + (lg & 1) * 4]) = o;
    }
  }
  __syncthreads();

  const unsigned short* WT = wt + 3 * 65536;
#pragma unroll
  for (int i = 0; i < 16; ++i) {
    int u = t + i * 512;
    int row = u >> 5, un = u & 31;
    int g = (un & 24) | ((un & 7) ^ (row & 7));
    gl2lds16(WT + row * 256 + g * 8, &L[u * 8]);
  }
  __syncthreads();

  f32x4 acc[4][2] = {};
#pragma unroll
  for (int ds = 0; ds < 8; ++ds) {
    const int ku = ds * 4 + lg;
    const int phys = ((ku & 24) | ((ku & 7) ^ lx)) << 3;
    bf16x8 af[4], bfr[2];
#pragma unroll
    for (int m = 0; m < 4; ++m)
      af[m] = *(const bf16x8*)(&L[65536 + (m * 16 + lr) * 256 + phys]);
#pragma unroll
    for (int n = 0; n < 2; ++n)
      bfr[n] = *(const bf16x8*)(&L[(w * 32 + n * 16 + lr) * 256 + phys]);
#pragma unroll
    for (int m = 0; m < 4; ++m)
#pragma unroll
      for (int n = 0; n < 2; ++n)
        acc[m][n] = mfma16(af[m], bfr[n], acc[m][n]);
  }

#pragma unroll
  for (int cgi = 0; cgi < 2; ++cgi) {
    int col = w * 32 + cgi * 16 + lr;
    float bb = bo[col];
#pragma unroll
    for (int m = 0; m < 4; ++m) {
      int rowg = b * 2048 + q0 + m * 16 + lg * 4;
#pragma unroll
      for (int r = 0; r < 4; ++r)
        out[(rowg + r) * 256 + col] = acc[m][cgi][r] + bb;
    }
  }
}

extern "C" void kernel_launch(void* const* d_in, const int* in_sizes, int n_in,
                              void* d_out, int out_size, void* d_ws, size_t ws_size,
                              hipStream_t stream) {
  const float* v    = (const float*)d_in[0];
  const float* k    = (const float*)d_in[1];
  const float* q    = (const float*)d_in[2];
  const float* mask = (const float*)d_in[3];
  const float* wq   = (const float*)d_in[4];
  const float* bq   = (const float*)d_in[5];
  const float* wk   = (const float*)d_in[6];
  const float* bk   = (const float*)d_in[7];
  const float* wv   = (const float*)d_in[8];
  const float* bv   = (const float*)d_in[9];
  const float* wo   = (const float*)d_in[10];
  const float* bo   = (const float*)d_in[11];
  float* out = (float*)d_out;
  char* ws = (char*)d_ws;

  // ws: wt 512K | mc 64K | gidx 64K | nct 4K | Qh 8M | Khc 8M | VhcT 8M
  unsigned short* wt  = (unsigned short*)(ws);
  float*          mc  = (float*)(ws + 524288);
  int*            gi  = (int*)(ws + 589824);
  int*            nc  = (int*)(ws + 655360);
  unsigned short* Qh  = (unsigned short*)(ws + 659456);
  unsigned short* Khc = (unsigned short*)(ws + 659456 + 8388608);
  unsigned short* VhT = (unsigned short*)(ws + 659456 + 2 * 8388608);

  prep_w<<<dim3(72), dim3(256), 0, stream>>>(wq, wk, wv, wo, mask, wt, mc, gi, nc);
  gemm_q<<<dim3(512), dim3(256), 0, stream>>>(q, bq, wt, Qh);
  gemm_kv<<<dim3(32, 8, 2), dim3(512), 0, stream>>>(k, v, bk, bv, wt, gi, nc, Khc, VhT);
  attn_out<<<dim3(32, 8), dim3(512), 0, stream>>>(Qh, Khc, VhT, mc, nc, wt, bo, out);
}

// Round 18
// 41.327 us; speedup vs baseline: 5.3624x; 1.1678x over previous
//
#include <hip/hip_runtime.h>

#define DEV __device__ __forceinline__

typedef __attribute__((ext_vector_type(4))) float f32x4;
typedef __bf16 bf16_t;
typedef __attribute__((ext_vector_type(4))) bf16_t bf16x4;
typedef __attribute__((ext_vector_type(8))) bf16_t bf16x8;
typedef __attribute__((ext_vector_type(8))) unsigned short us8;
typedef __attribute__((ext_vector_type(4))) unsigned short us4;

// B=8, S=2048, D_MODEL=256, H=4, DEPTH=64, BH=32, M=B*S=16384

DEV unsigned short f2bf(float f) {
  bf16_t h = (bf16_t)f;
  return __builtin_bit_cast(unsigned short, h);
}

DEV void gl2lds16(const void* g, void* l) {
  __builtin_amdgcn_global_load_lds(
      (const __attribute__((address_space(1))) unsigned int*)g,
      (__attribute__((address_space(3))) unsigned int*)l, 16, 0, 0);
}

DEV f32x4 mfma16(bf16x8 a, bf16x8 b, f32x4 c) {
  return __builtin_amdgcn_mfma_f32_16x16x32_bf16(a, b, c, 0, 0, 0);
}

// ---- prep: W transpose (blocks 0..63); per-batch COLUMN gather (64..71) ----
// Column s of batch b is invisible unless mask[s] < min_b + 1.45e-6 (sound).
// Deterministic prefix-sum compaction into gidx/mc; padded to 64 with mc=-1e30.
__global__ __launch_bounds__(256) void prep_w(
    const float* __restrict__ wq, const float* __restrict__ wk,
    const float* __restrict__ wv, const float* __restrict__ wo,
    const float* __restrict__ mask,
    unsigned short* __restrict__ wt, float* __restrict__ mc,
    int* __restrict__ gidx, int* __restrict__ nct) {
  const int t = threadIdx.x;
  if (blockIdx.x < 64) {
    __shared__ float T[64 * 65];
    const int mat = blockIdx.x >> 4, tn = (blockIdx.x >> 2) & 3, tk = blockIdx.x & 3;
    const int n0 = tn * 64, k0 = tk * 64;
    const float* W = (mat == 0) ? wq : (mat == 1) ? wk : (mat == 2) ? wv : wo;
    const int r0 = t >> 4, c = (t & 15) * 4;
#pragma unroll
    for (int i = 0; i < 4; ++i) {
      int rr = r0 + i * 16;
      f32x4 x = *(const f32x4*)(W + (k0 + rr) * 256 + n0 + c);
#pragma unroll
      for (int j = 0; j < 4; ++j) T[(c + j) * 65 + rr] = x[j];
    }
    __syncthreads();
#pragma unroll
    for (int i = 0; i < 2; ++i) {
      int u = t + i * 256;
      int n = u >> 3, seg = u & 7;
      us8 pk;
#pragma unroll
      for (int j = 0; j < 8; ++j) pk[j] = f2bf(T[n * 65 + seg * 8 + j]);
      *(us8*)(&wt[mat * 65536 + (n0 + n) * 256 + k0 + seg * 8]) = pk;
    }
  } else {
    __shared__ float redf[256];
    __shared__ int redi[256];
    const int b = blockIdx.x - 64;
    const float* mr = mask + b * 2048;
    f32x4 x0 = *(const f32x4*)(mr + t * 8);
    f32x4 x1 = *(const f32x4*)(mr + t * 8 + 4);
    float mv[8];
#pragma unroll
    for (int j = 0; j < 4; ++j) { mv[j] = x0[j]; mv[4 + j] = x1[j]; }
    float mn = mv[0];
#pragma unroll
    for (int j = 1; j < 8; ++j) mn = fminf(mn, mv[j]);
    redf[t] = mn;
    __syncthreads();
    for (int s = 128; s > 0; s >>= 1) {
      if (t < s) redf[t] = fminf(redf[t], redf[t + s]);
      __syncthreads();
    }
    const float minb = redf[0];
    const float thr = minb + 1.45e-6f;
    int myc = 0;
#pragma unroll
    for (int j = 0; j < 8; ++j) myc += (mv[j] < thr) ? 1 : 0;
    redi[t] = myc;
    __syncthreads();
    for (int s = 1; s < 256; s <<= 1) {
      int add = (t >= s) ? redi[t - s] : 0;
      __syncthreads();
      redi[t] += add;
      __syncthreads();
    }
    int pos = redi[t] - myc;
    const int cntb = redi[255];
#pragma unroll
    for (int j = 0; j < 8; ++j)
      if (mv[j] < thr) {
        gidx[b * 2048 + pos] = t * 8 + j;
        mc[b * 2048 + pos] = (mv[j] - minb) * -1.442695041e9f;
        ++pos;
      }
    if (t == 0) {
      int nt = (cntb + 63) >> 6;
      if (nt < 1) nt = 1;
      nct[b] = nt;
      for (int j = cntb; j < nt * 64; ++j) {
        gidx[b * 2048 + j] = 0;
        mc[b * 2048 + j] = -1.0e30f;
      }
    }
  }
}

// ---- MERGED projections, one launch. y=0: Q (512 strips, M32xN256xBK64).
// y=1: K/V for GATHERED rows (x = p*256 + b*32 + gt; early-exit vs nct).
// Unified 256 threads / 40 KB LDS -> 4 blocks/CU; KV runs concurrently under Q.
__global__ __launch_bounds__(256) void gemm_qkv(
    const float* __restrict__ qin, const float* __restrict__ kin,
    const float* __restrict__ vin,
    const float* __restrict__ bq, const float* __restrict__ bk,
    const float* __restrict__ bv,
    const unsigned short* __restrict__ wt, const int* __restrict__ gidx,
    const int* __restrict__ nct,
    unsigned short* __restrict__ Qh, unsigned short* __restrict__ Khc,
    unsigned short* __restrict__ VhcT) {
  __shared__ __align__(16) unsigned short At[64 * 64];      // 8 KB
  __shared__ __align__(16) unsigned short Bt[256 * 64];     // 32 KB
  const int t = threadIdx.x, lane = t & 63, w = t >> 6;     // 4 waves
  const int lr = lane & 15, lg = lane >> 4;
  const int lx = lr & 7;

  if (blockIdx.y == 0) {
    // ---------- Q path (R14-proven structure) ----------
    const int m0 = blockIdx.x * 32;
    const int as_row = t >> 3, as_seg = t & 7;
    const float* agp = qin + (m0 + as_row) * 256 + as_seg * 8;

    f32x4 acc[2][4] = {};
    for (int j = 0; j < 4; ++j) {
      const int k0 = j * 64;
#pragma unroll
      for (int i = 0; i < 8; ++i) {
        int u = t + i * 256;
        int row = u >> 3, g = (u & 7) ^ (row & 7);
        gl2lds16(wt + row * 256 + k0 + g * 8, &Bt[u * 8]);
      }
      {
        f32x4 x0 = *(const f32x4*)(agp + k0);
        f32x4 x1 = *(const f32x4*)(agp + k0 + 4);
        us8 pk;
#pragma unroll
        for (int jj = 0; jj < 4; ++jj) { pk[jj] = f2bf(x0[jj]); pk[jj + 4] = f2bf(x1[jj]); }
        *(us8*)(&At[(as_row << 6) + ((as_seg ^ (as_row & 7)) << 3)]) = pk;
      }
      __syncthreads();
#pragma unroll
      for (int ds = 0; ds < 2; ++ds) {
        const int ku = (ds << 2) | lg;
        const int phys = (ku ^ lx) << 3;
        bf16x8 af[2], bfr[4];
#pragma unroll
        for (int m = 0; m < 2; ++m)
          af[m] = *(const bf16x8*)(&At[((m * 16 + lr) << 6) + phys]);
#pragma unroll
        for (int cg = 0; cg < 4; ++cg)
          bfr[cg] = *(const bf16x8*)(&Bt[((w * 64 + cg * 16 + lr) << 6) + phys]);
#pragma unroll
        for (int m = 0; m < 2; ++m)
#pragma unroll
          for (int cg = 0; cg < 4; ++cg)
            acc[m][cg] = mfma16(af[m], bfr[cg], acc[m][cg]);
      }
      __syncthreads();
    }

    const int b = m0 >> 11, s0 = m0 & 2047;
    const int bh = b * 4 + w;
#pragma unroll
    for (int cg = 0; cg < 4; ++cg) {
      int d = cg * 16 + lr;
      float bb = bq[w * 64 + d];
#pragma unroll
      for (int m = 0; m < 2; ++m) {
        int sb = s0 + m * 16 + lg * 4;
#pragma unroll
        for (int r = 0; r < 4; ++r)
          Qh[(bh * 2048 + sb + r) * 64 + d] = f2bf(acc[m][cg][r] + bb);
      }
    }
  } else {
    // ---------- K/V path (gathered rows; tiny active set) ----------
    const int x = blockIdx.x;
    const int p = x >> 8, b = (x >> 5) & 7, gt = x & 31;
    if (gt >= nct[b]) return;
    const float* A    = p ? vin : kin;
    const float* bias = p ? bv : bk;
    const unsigned short* WT = wt + (p ? 2 : 1) * 65536;
    const int* gi = gidx + b * 2048 + gt * 64;

    f32x4 acc[4][4] = {};   // [m rows][cg cols], wave w = head w (64 cols)
    for (int j = 0; j < 4; ++j) {
      const int k0 = j * 64;
#pragma unroll
      for (int i = 0; i < 8; ++i) {
        int u = t + i * 256;
        int row = u >> 3, g = (u & 7) ^ (row & 7);
        gl2lds16(WT + row * 256 + k0 + g * 8, &Bt[u * 8]);
      }
#pragma unroll
      for (int i = 0; i < 2; ++i) {            // 64 rows x 8 segs = 512 slots
        int slot = t + i * 256;
        int row = slot >> 3, seg = slot & 7;
        const float* src = A + (b * 2048 + gi[row]) * 256 + k0 + seg * 8;
        f32x4 x0 = *(const f32x4*)src;
        f32x4 x1 = *(const f32x4*)(src + 4);
        us8 pk;
#pragma unroll
        for (int jj = 0; jj < 4; ++jj) { pk[jj] = f2bf(x0[jj]); pk[jj + 4] = f2bf(x1[jj]); }
        *(us8*)(&At[(row << 6) + ((seg ^ (row & 7)) << 3)]) = pk;
      }
      __syncthreads();
#pragma unroll
      for (int ds = 0; ds < 2; ++ds) {
        const int ku = (ds << 2) | lg;
        const int phys = (ku ^ lx) << 3;
        bf16x8 af[4], bfr[4];
#pragma unroll
        for (int m = 0; m < 4; ++m)
          af[m] = *(const bf16x8*)(&At[((m * 16 + lr) << 6) + phys]);
#pragma unroll
        for (int cg = 0; cg < 4; ++cg)
          bfr[cg] = *(const bf16x8*)(&Bt[((w * 64 + cg * 16 + lr) << 6) + phys]);
#pragma unroll
        for (int m = 0; m < 4; ++m)
#pragma unroll
          for (int cg = 0; cg < 4; ++cg)
            acc[m][cg] = mfma16(af[m], bfr[cg], acc[m][cg]);
      }
      __syncthreads();
    }

    const int bh = b * 4 + w;
#pragma unroll
    for (int cg = 0; cg < 4; ++cg) {
      int d = cg * 16 + lr;
      float bb = bias[w * 64 + d];
#pragma unroll
      for (int m = 0; m < 4; ++m) {
        int pos = gt * 64 + m * 16 + lg * 4;
        if (p) {
          us4 o;
#pragma unroll
          for (int r = 0; r < 4; ++r) o[r] = f2bf(acc[m][cg][r] + bb);
          *(us4*)(&VhcT[(bh * 64 + d) * 2048 + pos]) = o;
        } else {
#pragma unroll
          for (int r = 0; r < 4; ++r)
            Khc[(bh * 2048 + pos + r) * 64 + d] = f2bf(acc[m][cg][r] + bb);
        }
      }
    }
  }
}

// ---- FUSED attention + output projection over COMPACTED tiles ----
__global__ __launch_bounds__(512) void attn_out(
    const unsigned short* __restrict__ Qh, const unsigned short* __restrict__ Kh,
    const unsigned short* __restrict__ VhT, const float* __restrict__ mc,
    const int* __restrict__ nct, const unsigned short* __restrict__ wt,
    const float* __restrict__ bo, float* __restrict__ out) {
  __shared__ __align__(16) unsigned short L[81920];   // 160 KB
  const int b = blockIdx.y;
  const int q0 = blockIdx.x * 64;
  const int t = threadIdx.x, lane = t & 63, w = t >> 6;
  const int lr = lane & 15, lg = lane >> 4;
  const int h = w >> 1, ch = w & 1;
  const int bh = b * 4 + h;
  const float* mrow = mc + b * 2048;
  const int lx = lr & 7;
  const int lgh = lg >> 1, lgo = (lg & 1) * 4;

  bf16x8 qf[2][2];
#pragma unroll
  for (int cc = 0; cc < 2; ++cc)
#pragma unroll
    for (int ds = 0; ds < 2; ++ds)
      qf[cc][ds] = *(const bf16x8*)(Qh + (bh * 2048 + q0 + ch * 32 + cc * 16 + lr) * 64 + ds * 32 + lg * 8);

  f32x4 accO[2][4] = {};
  float mrun[2] = {-3.0e38f, -3.0e38f}, lrun[2] = {0.f, 0.f};

#define STAGE(buf, kv)                                                        \
  {                                                                           \
    _Pragma("unroll")                                                         \
    for (int i = 0; i < 4; ++i) {                                             \
      int u = t + i * 512;                                                    \
      int hh = u >> 9, vv = u & 511;                                          \
      int row = vv >> 3, g = (vv & 7) ^ (row & 7);                            \
      gl2lds16(Kh + ((b * 4 + hh) * 2048 + (kv) + row) * 64 + g * 8,          \
               &L[((buf) * 16384 + hh * 4096 + vv * 8)]);                     \
      gl2lds16(VhT + ((b * 4 + hh) * 64 + row) * 2048 + (kv) + g * 8,         \
               &L[(32768 + (buf) * 16384 + hh * 4096 + vv * 8)]);             \
    }                                                                         \
  }

  const int cnt = nct[b];
  STAGE(0, 0)
  __syncthreads();
  int cur = 0;

  for (int j = 0; j < cnt; ++j) {
    const int kv0 = j * 64;
    if (j + 1 < cnt) STAGE(cur ^ 1, kv0 + 64)

    const int kb_base = cur * 16384 + h * 4096;
    const int vb_base = 32768 + kb_base;

#pragma unroll
    for (int cc = 0; cc < 2; ++cc) {
      f32x4 accS[4] = {};
      __builtin_amdgcn_s_setprio(1);
#pragma unroll
      for (int kb = 0; kb < 4; ++kb)
#pragma unroll
        for (int ds = 0; ds < 2; ++ds) {
          bf16x8 kf = *(const bf16x8*)(&L[kb_base + (((kb * 16 + lr) << 3) | (((ds << 2) | lg) ^ lx)) * 8]);
          accS[kb] = mfma16(kf, qf[cc][ds], accS[kb]);
        }
      __builtin_amdgcn_s_setprio(0);

      f32x4 sv[4];
#pragma unroll
      for (int kb = 0; kb < 4; ++kb) {
        f32x4 mk = *(const f32x4*)(mrow + kv0 + kb * 16 + lg * 4);
        sv[kb] = accS[kb] * 0.1803368801f + mk;
      }
      float mx0 = fmaxf(fmaxf(sv[0][0], sv[0][1]), fmaxf(sv[0][2], sv[0][3]));
      float mx1 = fmaxf(fmaxf(sv[1][0], sv[1][1]), fmaxf(sv[1][2], sv[1][3]));
      float mx2 = fmaxf(fmaxf(sv[2][0], sv[2][1]), fmaxf(sv[2][2], sv[2][3]));
      float mx3 = fmaxf(fmaxf(sv[3][0], sv[3][1]), fmaxf(sv[3][2], sv[3][3]));
      float mx = fmaxf(fmaxf(mx0, mx1), fmaxf(mx2, mx3));
      mx = fmaxf(mx, __shfl_xor(mx, 16));
      mx = fmaxf(mx, __shfl_xor(mx, 32));
      float mnew = fmaxf(mrun[cc], mx);
      float al = __builtin_amdgcn_exp2f(mrun[cc] - mnew);
      mrun[cc] = mnew;

      float px[4][4];
      float lsum = 0.f;
#pragma unroll
      for (int kb = 0; kb < 4; ++kb) {
        float s = 0.f;
#pragma unroll
        for (int r = 0; r < 4; ++r) {
          px[kb][r] = __builtin_amdgcn_exp2f(sv[kb][r] - mnew);
          s += px[kb][r];
        }
        lsum += s;
      }
      lsum += __shfl_xor(lsum, 16);
      lsum += __shfl_xor(lsum, 32);
      lrun[cc] = lrun[cc] * al + lsum;
#pragma unroll
      for (int db = 0; db < 4; ++db) accO[cc][db] *= al;

      bf16x8 pf[2];
#pragma unroll
      for (int ks = 0; ks < 2; ++ks) {
        bf16x8 p;
#pragma unroll
        for (int r = 0; r < 4; ++r) {
          p[r]     = (bf16_t)px[2 * ks][r];
          p[r + 4] = (bf16_t)px[2 * ks + 1][r];
        }
        pf[ks] = p;
      }

      __builtin_amdgcn_s_setprio(1);
#pragma unroll
      for (int ks = 0; ks < 2; ++ks)
#pragma unroll
        for (int db = 0; db < 4; ++db) {
          int row = db * 16 + lr;
          int u0 = (row << 3) | (((ks << 2) | lgh) ^ lx);
          int u1 = (row << 3) | (((ks << 2) | 2 | lgh) ^ lx);
          bf16x4 v0 = *(const bf16x4*)(&L[vb_base + u0 * 8 + lgo]);
          bf16x4 v1 = *(const bf16x4*)(&L[vb_base + u1 * 8 + lgo]);
          bf16x8 vf = __builtin_shufflevector(v0, v1, 0, 1, 2, 3, 4, 5, 6, 7);
          accO[cc][db] = mfma16(vf, pf[ks], accO[cc][db]);
        }
      __builtin_amdgcn_s_setprio(0);
    }

    __syncthreads();
    cur ^= 1;
  }
#undef STAGE

  // epilogue: O -> LDS bf16 (swizzled), stage WoT, out = O @ Wo + bo
#pragma unroll
  for (int cc = 0; cc < 2; ++cc) {
    const float inv = __builtin_amdgcn_rcpf(lrun[cc]);
    const int row = ch * 32 + cc * 16 + lr;
#pragma unroll
    for (int db = 0; db < 4; ++db) {
      us4 o;
#pragma unroll
      for (int r = 0; r < 4; ++r) o[r] = f2bf(accO[cc][db][r] * inv);
      int un = h * 8 + db * 2 + (lg >> 1);
      int phys = (un & 24) | ((un & 7) ^ (row & 7));
      *(us4*)(&L[65536 + row * 256 + phys * 8 + (lg & 1) * 4]) = o;
    }
  }
  __syncthreads();

  const unsigned short* WT = wt + 3 * 65536;
#pragma unroll
  for (int i = 0; i < 16; ++i) {
    int u = t + i * 512;
    int row = u >> 5, un = u & 31;
    int g = (un & 24) | ((un & 7) ^ (row & 7));
    gl2lds16(WT + row * 256 + g * 8, &L[u * 8]);
  }
  __syncthreads();

  f32x4 acc[4][2] = {};
#pragma unroll
  for (int ds = 0; ds < 8; ++ds) {
    const int ku = ds * 4 + lg;
    const int phys = ((ku & 24) | ((ku & 7) ^ lx)) << 3;
    bf16x8 af[4], bfr[2];
#pragma unroll
    for (int m = 0; m < 4; ++m)
      af[m] = *(const bf16x8*)(&L[65536 + (m * 16 + lr) * 256 + phys]);
#pragma unroll
    for (int n = 0; n < 2; ++n)
      bfr[n] = *(const bf16x8*)(&L[(w * 32 + n * 16 + lr) * 256 + phys]);
#pragma unroll
    for (int m = 0; m < 4; ++m)
#pragma unroll
      for (int n = 0; n < 2; ++n)
        acc[m][n] = mfma16(af[m], bfr[n], acc[m][n]);
  }

#pragma unroll
  for (int cgi = 0; cgi < 2; ++cgi) {
    int col = w * 32 + cgi * 16 + lr;
    float bb = bo[col];
#pragma unroll
    for (int m = 0; m < 4; ++m) {
      int rowg = b * 2048 + q0 + m * 16 + lg * 4;
#pragma unroll
      for (int r = 0; r < 4; ++r)
        out[(rowg + r) * 256 + col] = acc[m][cgi][r] + bb;
    }
  }
}

extern "C" void kernel_launch(void* const* d_in, const int* in_sizes, int n_in,
                              void* d_out, int out_size, void* d_ws, size_t ws_size,
                              hipStream_t stream) {
  const float* v    = (const float*)d_in[0];
  const float* k    = (const float*)d_in[1];
  const float* q    = (const float*)d_in[2];
  const float* mask = (const float*)d_in[3];
  const float* wq   = (const float*)d_in[4];
  const float* bq   = (const float*)d_in[5];
  const float* wk   = (const float*)d_in[6];
  const float* bk   = (const float*)d_in[7];
  const float* wv   = (const float*)d_in[8];
  const float* bv   = (const float*)d_in[9];
  const float* wo   = (const float*)d_in[10];
  const float* bo   = (const float*)d_in[11];
  float* out = (float*)d_out;
  char* ws = (char*)d_ws;

  // ws: wt 512K | mc 64K | gidx 64K | nct 4K | Qh 8M | Khc 8M | VhcT 8M
  unsigned short* wt  = (unsigned short*)(ws);
  float*          mc  = (float*)(ws + 524288);
  int*            gi  = (int*)(ws + 589824);
  int*            nc  = (int*)(ws + 655360);
  unsigned short* Qh  = (unsigned short*)(ws + 659456);
  unsigned short* Khc = (unsigned short*)(ws + 659456 + 8388608);
  unsigned short* VhT = (unsigned short*)(ws + 659456 + 2 * 8388608);

  prep_w<<<dim3(72), dim3(256), 0, stream>>>(wq, wk, wv, wo, mask, wt, mc, gi, nc);
  gemm_qkv<<<dim3(512, 2), dim3(256), 0, stream>>>(q, k, v, bq, bk, bv, wt, gi, nc, Qh, Khc, VhT);
  attn_out<<<dim3(32, 8), dim3(512), 0, stream>>>(Qh, Khc, VhT, mc, nc, wt, bo, out);
}

// Round 19
// 39.070 us; speedup vs baseline: 5.6723x; 1.0578x over previous
//
#include <hip/hip_runtime.h>

#define DEV __device__ __forceinline__

typedef __attribute__((ext_vector_type(4))) float f32x4;
typedef __bf16 bf16_t;
typedef __attribute__((ext_vector_type(4))) bf16_t bf16x4;
typedef __attribute__((ext_vector_type(8))) bf16_t bf16x8;
typedef __attribute__((ext_vector_type(8))) unsigned short us8;
typedef __attribute__((ext_vector_type(4))) unsigned short us4;

// B=8, S=2048, D_MODEL=256, H=4, DEPTH=64, BH=32, M=B*S=16384

DEV unsigned short f2bf(float f) {
  bf16_t h = (bf16_t)f;
  return __builtin_bit_cast(unsigned short, h);
}

DEV void gl2lds16(const void* g, void* l) {
  __builtin_amdgcn_global_load_lds(
      (const __attribute__((address_space(1))) unsigned int*)g,
      (__attribute__((address_space(3))) unsigned int*)l, 16, 0, 0);
}

DEV f32x4 mfma16(bf16x8 a, bf16x8 b, f32x4 c) {
  return __builtin_amdgcn_mfma_f32_16x16x32_bf16(a, b, c, 0, 0, 0);
}

// ---- LAUNCH 1: blocks 0..31 transpose wq/wo; blocks 32..39 gather+project K/V.
// Gather: col s of batch b survives iff mask[s] < min_b + 1.45e-6 (sound bound).
// K/V projected ONLY for surviving rows, via coalesced f32 dot-products
// (thread n covers output col n; W rows are n-contiguous; A value broadcasts).
__global__ __launch_bounds__(512) void prep_kv(
    const float* __restrict__ wq, const float* __restrict__ wo,
    const float* __restrict__ wk, const float* __restrict__ wv,
    const float* __restrict__ bk, const float* __restrict__ bv,
    const float* __restrict__ mask,
    const float* __restrict__ kin, const float* __restrict__ vin,
    unsigned short* __restrict__ wt, float* __restrict__ mc,
    int* __restrict__ nct,
    unsigned short* __restrict__ Khc, unsigned short* __restrict__ VhcT) {
  const int t = threadIdx.x;
  if (blockIdx.x < 32) {
    __shared__ float T[64 * 65];
    const int mat = blockIdx.x >> 4, tn = (blockIdx.x >> 2) & 3, tk = blockIdx.x & 3;
    const int n0 = tn * 64, k0 = tk * 64;
    const float* W = (mat == 0) ? wq : wo;
    if (t < 256) {
      const int r0 = t >> 4, c = (t & 15) * 4;
#pragma unroll
      for (int i = 0; i < 4; ++i) {
        int rr = r0 + i * 16;
        f32x4 x = *(const f32x4*)(W + (k0 + rr) * 256 + n0 + c);
#pragma unroll
        for (int j = 0; j < 4; ++j) T[(c + j) * 65 + rr] = x[j];
      }
    }
    __syncthreads();
    if (t < 256) {
#pragma unroll
      for (int i = 0; i < 2; ++i) {
        int u = t + i * 256;
        int n = u >> 3, seg = u & 7;
        us8 pk;
#pragma unroll
        for (int j = 0; j < 8; ++j) pk[j] = f2bf(T[n * 65 + seg * 8 + j]);
        *(us8*)(&wt[mat * 65536 + (n0 + n) * 256 + k0 + seg * 8]) = pk;
      }
    }
  } else {
    __shared__ float redf[512];
    __shared__ int redi[512];
    __shared__ int srows[2048];
    const int b = blockIdx.x - 32;
    f32x4 mv4 = *(const f32x4*)(mask + b * 2048 + t * 4);
    float mv[4] = {mv4[0], mv4[1], mv4[2], mv4[3]};
    float mn = fminf(fminf(mv[0], mv[1]), fminf(mv[2], mv[3]));
    redf[t] = mn;
    __syncthreads();
    for (int s = 256; s > 0; s >>= 1) {
      if (t < s) redf[t] = fminf(redf[t], redf[t + s]);
      __syncthreads();
    }
    const float minb = redf[0];
    const float thr = minb + 1.45e-6f;
    int myc = 0;
#pragma unroll
    for (int j = 0; j < 4; ++j) myc += (mv[j] < thr) ? 1 : 0;
    redi[t] = myc;
    __syncthreads();
    for (int s = 1; s < 512; s <<= 1) {
      int add = (t >= s) ? redi[t - s] : 0;
      __syncthreads();
      redi[t] += add;
      __syncthreads();
    }
    int pos = redi[t] - myc;
    const int cnt = redi[511];
#pragma unroll
    for (int j = 0; j < 4; ++j)
      if (mv[j] < thr) {
        srows[pos] = t * 4 + j;
        mc[b * 2048 + pos] = (mv[j] - minb) * -1.442695041e9f;
        ++pos;
      }
    if (t == 0) {
      int nt = (cnt + 63) >> 6;
      if (nt < 1) nt = 1;
      nct[b] = nt;
      for (int j = cnt; j < nt * 64; ++j) mc[b * 2048 + j] = -1.0e30f;
    }
    __syncthreads();

    // project K and V for each surviving row (typically 1-3 rows)
    const int n = t & 255, half = t >> 8;
    for (int r = 0; r < cnt; ++r) {
      const int srow = srows[r];
      // K
      {
        const float* a = kin + (b * 2048 + srow) * 256 + half * 128;
        const float* wrow = wk + half * 128 * 256 + n;
        float acc = 0.f;
#pragma unroll 8
        for (int kk = 0; kk < 128; ++kk) acc += a[kk] * wrow[kk * 256];
        redf[t] = acc;
        __syncthreads();
        if (half == 0) {
          float s = acc + redf[t + 256] + bk[n];
          Khc[((b * 4 + (n >> 6)) * 2048 + r) * 64 + (n & 63)] = f2bf(s);
        }
        __syncthreads();
      }
      // V
      {
        const float* a = vin + (b * 2048 + srow) * 256 + half * 128;
        const float* wrow = wv + half * 128 * 256 + n;
        float acc = 0.f;
#pragma unroll 8
        for (int kk = 0; kk < 128; ++kk) acc += a[kk] * wrow[kk * 256];
        redf[t] = acc;
        __syncthreads();
        if (half == 0) {
          float s = acc + redf[t + 256] + bv[n];
          VhcT[((b * 4 + (n >> 6)) * 64 + (n & 63)) * 2048 + r] = f2bf(s);
        }
        __syncthreads();
      }
    }
  }
}

// ---- LAUNCH 2: fused Q-projection + attention + output projection.
// Prologue: stage wq^T (128KB) + 64 q-rows (32KB) = 160KB, 1 barrier, 64 MFMA,
// Q tile -> LDS (no HBM round trip). Then compacted-attention + Wo epilogue.
__global__ __launch_bounds__(512) void attn_fused(
    const float* __restrict__ qin, const float* __restrict__ bq,
    const unsigned short* __restrict__ Khc, const unsigned short* __restrict__ VhcT,
    const float* __restrict__ mc, const int* __restrict__ nct,
    const unsigned short* __restrict__ wt, const float* __restrict__ bo,
    float* __restrict__ out) {
  __shared__ __align__(16) unsigned short L[81920];   // 160 KB
  const int b = blockIdx.y;
  const int q0 = blockIdx.x * 64;
  const int t = threadIdx.x, lane = t & 63, w = t >> 6;
  const int lr = lane & 15, lg = lane >> 4;
  const int h = w >> 1, ch = w & 1;
  const float* mrow = mc + b * 2048;
  const int lx = lr & 7;
  const int lgh = lg >> 1, lgo = (lg & 1) * 4;

  // ---- Q projection prologue ----
#pragma unroll
  for (int i = 0; i < 16; ++i) {            // WqT: 8192 us8 units at L[0]
    int u = t + i * 512;
    int row = u >> 5, un = u & 31;
    int g = (un & 24) | ((un & 7) ^ (row & 7));
    gl2lds16(wt + row * 256 + g * 8, &L[u * 8]);
  }
#pragma unroll
  for (int i = 0; i < 4; ++i) {             // A (q rows) -> bf16 at us 65536
    int u = t + i * 512;
    int row = u >> 5, un = u & 31;
    const float* src = qin + (b * 2048 + q0 + row) * 256 + un * 8;
    f32x4 x0 = *(const f32x4*)src;
    f32x4 x1 = *(const f32x4*)(src + 4);
    us8 pk;
#pragma unroll
    for (int jj = 0; jj < 4; ++jj) { pk[jj] = f2bf(x0[jj]); pk[jj + 4] = f2bf(x1[jj]); }
    *(us8*)(&L[65536 + row * 256 + (((un & 24) | ((un & 7) ^ (row & 7))) << 3)]) = pk;
  }
  __syncthreads();

  f32x4 aq[2][4] = {};
#pragma unroll
  for (int ds8 = 0; ds8 < 8; ++ds8) {
    int ku = ds8 * 4 + lg;
    int phys = ((ku & 24) | ((ku & 7) ^ lx)) << 3;
    bf16x8 af[2], bfr[4];
#pragma unroll
    for (int cc = 0; cc < 2; ++cc)
      af[cc] = *(const bf16x8*)(&L[65536 + (ch * 32 + cc * 16 + lr) * 256 + phys]);
#pragma unroll
    for (int n = 0; n < 4; ++n)
      bfr[n] = *(const bf16x8*)(&L[(h * 64 + n * 16 + lr) * 256 + phys]);
#pragma unroll
    for (int cc = 0; cc < 2; ++cc)
#pragma unroll
      for (int n = 0; n < 4; ++n)
        aq[cc][n] = mfma16(af[cc], bfr[n], aq[cc][n]);
  }
  __syncthreads();                          // WqT + A reads complete
  // write Q tile (bf16, swizzled) over the A region
#pragma unroll
  for (int cc = 0; cc < 2; ++cc)
#pragma unroll
    for (int n = 0; n < 4; ++n) {
      int col = h * 64 + n * 16 + lr;
      int un = col >> 3;
      float bb = bq[col];
#pragma unroll
      for (int r = 0; r < 4; ++r) {
        int row = ch * 32 + cc * 16 + lg * 4 + r;
        int phys = (un & 24) | ((un & 7) ^ (row & 7));
        L[65536 + row * 256 + phys * 8 + (col & 7)] = f2bf(aq[cc][n][r] + bb);
      }
    }
  __syncthreads();

  bf16x8 qf[2][2];
#pragma unroll
  for (int cc = 0; cc < 2; ++cc)
#pragma unroll
    for (int ds = 0; ds < 2; ++ds) {
      int row = ch * 32 + cc * 16 + lr;
      int un = h * 8 + ds * 4 + lg;
      int phys = (un & 24) | ((un & 7) ^ lx);
      qf[cc][ds] = *(const bf16x8*)(&L[65536 + row * 256 + phys * 8]);
    }
  __syncthreads();                          // Q tile reads done before K/V staging

  // ---- compacted attention main loop ----
  f32x4 accO[2][4] = {};
  float mrun[2] = {-3.0e38f, -3.0e38f}, lrun[2] = {0.f, 0.f};

#define STAGE(buf, kv)                                                        \
  {                                                                           \
    _Pragma("unroll")                                                         \
    for (int i = 0; i < 4; ++i) {                                             \
      int u = t + i * 512;                                                    \
      int hh = u >> 9, vv = u & 511;                                          \
      int row = vv >> 3, g = (vv & 7) ^ (row & 7);                            \
      gl2lds16(Khc + ((b * 4 + hh) * 2048 + (kv) + row) * 64 + g * 8,         \
               &L[((buf) * 16384 + hh * 4096 + vv * 8)]);                     \
      gl2lds16(VhcT + ((b * 4 + hh) * 64 + row) * 2048 + (kv) + g * 8,        \
               &L[(32768 + (buf) * 16384 + hh * 4096 + vv * 8)]);             \
    }                                                                         \
  }

  const int cnt = nct[b];
  STAGE(0, 0)
  __syncthreads();
  int cur = 0;

  for (int j = 0; j < cnt; ++j) {
    const int kv0 = j * 64;
    if (j + 1 < cnt) STAGE(cur ^ 1, kv0 + 64)

    const int kb_base = cur * 16384 + h * 4096;
    const int vb_base = 32768 + kb_base;

#pragma unroll
    for (int cc = 0; cc < 2; ++cc) {
      f32x4 accS[4] = {};
      __builtin_amdgcn_s_setprio(1);
#pragma unroll
      for (int kb = 0; kb < 4; ++kb)
#pragma unroll
        for (int ds = 0; ds < 2; ++ds) {
          bf16x8 kf = *(const bf16x8*)(&L[kb_base + (((kb * 16 + lr) << 3) | (((ds << 2) | lg) ^ lx)) * 8]);
          accS[kb] = mfma16(kf, qf[cc][ds], accS[kb]);
        }
      __builtin_amdgcn_s_setprio(0);

      f32x4 sv[4];
#pragma unroll
      for (int kb = 0; kb < 4; ++kb) {
        f32x4 mk = *(const f32x4*)(mrow + kv0 + kb * 16 + lg * 4);
        sv[kb] = accS[kb] * 0.1803368801f + mk;
      }
      float mx0 = fmaxf(fmaxf(sv[0][0], sv[0][1]), fmaxf(sv[0][2], sv[0][3]));
      float mx1 = fmaxf(fmaxf(sv[1][0], sv[1][1]), fmaxf(sv[1][2], sv[1][3]));
      float mx2 = fmaxf(fmaxf(sv[2][0], sv[2][1]), fmaxf(sv[2][2], sv[2][3]));
      float mx3 = fmaxf(fmaxf(sv[3][0], sv[3][1]), fmaxf(sv[3][2], sv[3][3]));
      float mx = fmaxf(fmaxf(mx0, mx1), fmaxf(mx2, mx3));
      mx = fmaxf(mx, __shfl_xor(mx, 16));
      mx = fmaxf(mx, __shfl_xor(mx, 32));
      float mnew = fmaxf(mrun[cc], mx);
      float al = __builtin_amdgcn_exp2f(mrun[cc] - mnew);
      mrun[cc] = mnew;

      float px[4][4];
      float lsum = 0.f;
#pragma unroll
      for (int kb = 0; kb < 4; ++kb) {
        float s = 0.f;
#pragma unroll
        for (int r = 0; r < 4; ++r) {
          px[kb][r] = __builtin_amdgcn_exp2f(sv[kb][r] - mnew);
          s += px[kb][r];
        }
        lsum += s;
      }
      lsum += __shfl_xor(lsum, 16);
      lsum += __shfl_xor(lsum, 32);
      lrun[cc] = lrun[cc] * al + lsum;
#pragma unroll
      for (int db = 0; db < 4; ++db) accO[cc][db] *= al;

      bf16x8 pf[2];
#pragma unroll
      for (int ks = 0; ks < 2; ++ks) {
        bf16x8 p;
#pragma unroll
        for (int r = 0; r < 4; ++r) {
          p[r]     = (bf16_t)px[2 * ks][r];
          p[r + 4] = (bf16_t)px[2 * ks + 1][r];
        }
        pf[ks] = p;
      }

      __builtin_amdgcn_s_setprio(1);
#pragma unroll
      for (int ks = 0; ks < 2; ++ks)
#pragma unroll
        for (int db = 0; db < 4; ++db) {
          int row = db * 16 + lr;
          int u0 = (row << 3) | (((ks << 2) | lgh) ^ lx);
          int u1 = (row << 3) | (((ks << 2) | 2 | lgh) ^ lx);
          bf16x4 v0 = *(const bf16x4*)(&L[vb_base + u0 * 8 + lgo]);
          bf16x4 v1 = *(const bf16x4*)(&L[vb_base + u1 * 8 + lgo]);
          bf16x8 vf = __builtin_shufflevector(v0, v1, 0, 1, 2, 3, 4, 5, 6, 7);
          accO[cc][db] = mfma16(vf, pf[ks], accO[cc][db]);
        }
      __builtin_amdgcn_s_setprio(0);
    }

    __syncthreads();
    cur ^= 1;
  }
#undef STAGE

  // ---- epilogue: O -> LDS bf16 (swizzled), stage WoT, out = O @ Wo + bo ----
#pragma unroll
  for (int cc = 0; cc < 2; ++cc) {
    const float inv = __builtin_amdgcn_rcpf(lrun[cc]);
    const int row = ch * 32 + cc * 16 + lr;
#pragma unroll
    for (int db = 0; db < 4; ++db) {
      us4 o;
#pragma unroll
      for (int r = 0; r < 4; ++r) o[r] = f2bf(accO[cc][db][r] * inv);
      int un = h * 8 + db * 2 + (lg >> 1);
      int phys = (un & 24) | ((un & 7) ^ (row & 7));
      *(us4*)(&L[65536 + row * 256 + phys * 8 + (lg & 1) * 4]) = o;
    }
  }
  __syncthreads();

  const unsigned short* WT = wt + 65536;    // woT
#pragma unroll
  for (int i = 0; i < 16; ++i) {
    int u = t + i * 512;
    int row = u >> 5, un = u & 31;
    int g = (un & 24) | ((un & 7) ^ (row & 7));
    gl2lds16(WT + row * 256 + g * 8, &L[u * 8]);
  }
  __syncthreads();

  f32x4 acc[4][2] = {};
#pragma unroll
  for (int ds = 0; ds < 8; ++ds) {
    const int ku = ds * 4 + lg;
    const int phys = ((ku & 24) | ((ku & 7) ^ lx)) << 3;
    bf16x8 af[4], bfr[2];
#pragma unroll
    for (int m = 0; m < 4; ++m)
      af[m] = *(const bf16x8*)(&L[65536 + (m * 16 + lr) * 256 + phys]);
#pragma unroll
    for (int n = 0; n < 2; ++n)
      bfr[n] = *(const bf16x8*)(&L[(w * 32 + n * 16 + lr) * 256 + phys]);
#pragma unroll
    for (int m = 0; m < 4; ++m)
#pragma unroll
      for (int n = 0; n < 2; ++n)
        acc[m][n] = mfma16(af[m], bfr[n], acc[m][n]);
  }

#pragma unroll
  for (int cgi = 0; cgi < 2; ++cgi) {
    int col = w * 32 + cgi * 16 + lr;
    float bb = bo[col];
#pragma unroll
    for (int m = 0; m < 4; ++m) {
      int rowg = b * 2048 + q0 + m * 16 + lg * 4;
#pragma unroll
      for (int r = 0; r < 4; ++r)
        out[(rowg + r) * 256 + col] = acc[m][cgi][r] + bb;
    }
  }
}

extern "C" void kernel_launch(void* const* d_in, const int* in_sizes, int n_in,
                              void* d_out, int out_size, void* d_ws, size_t ws_size,
                              hipStream_t stream) {
  const float* v    = (const float*)d_in[0];
  const float* k    = (const float*)d_in[1];
  const float* q    = (const float*)d_in[2];
  const float* mask = (const float*)d_in[3];
  const float* wq   = (const float*)d_in[4];
  const float* bq   = (const float*)d_in[5];
  const float* wk   = (const float*)d_in[6];
  const float* bk   = (const float*)d_in[7];
  const float* wv   = (const float*)d_in[8];
  const float* bv   = (const float*)d_in[9];
  const float* wo   = (const float*)d_in[10];
  const float* bo   = (const float*)d_in[11];
  float* out = (float*)d_out;
  char* ws = (char*)d_ws;

  // ws: wt 256K (wqT, woT) | mc 64K | nct 4K | Khc 8M | VhcT 8M
  unsigned short* wt  = (unsigned short*)(ws);
  float*          mc  = (float*)(ws + 262144);
  int*            nc  = (int*)(ws + 327680);
  unsigned short* Khc = (unsigned short*)(ws + 331776);
  unsigned short* VhT = (unsigned short*)(ws + 331776 + 8388608);

  prep_kv<<<dim3(40), dim3(512), 0, stream>>>(wq, wo, wk, wv, bk, bv, mask, k, v,
                                              wt, mc, nc, Khc, VhT);
  attn_fused<<<dim3(32, 8), dim3(512), 0, stream>>>(q, bq, Khc, VhT, mc, nc, wt, bo, out);
}